// Round 2
// baseline (7585.208 us; speedup 1.0000x reference)
//
#include <hip/hip_runtime.h>
#include <hip/hip_bf16.h>

// Problem constants (from reference)
#define L_SEQ   2048
#define DMODEL  1024
#define DINNER  2048
#define DSTATE  16
#define DTRANK  64
#define DCONV   4
#define NLAYER  4
#define XDIM    96   // DTRANK + 2*DSTATE

__device__ __forceinline__ float bf2f(unsigned short u) {
    union { unsigned int i; float f; } v; v.i = ((unsigned int)u) << 16; return v.f;
}
__device__ __forceinline__ unsigned short f2bf(float f) {
    union { float f; unsigned int i; } v; v.f = f;
    unsigned int x = v.i;
    unsigned int r = (x + 0x7fffu + ((x >> 16) & 1u)) >> 16;  // RTNE
    return (unsigned short)r;
}
// scalar load of input element idx, dtype selected by bf flag
__device__ __forceinline__ float ldin(const void* p, size_t idx, bool bf) {
    return bf ? bf2f(((const unsigned short*)p)[idx]) : ((const float*)p)[idx];
}

// ---------------------------------------------------------------------------
// Dtype detector: A_log[0] = log(1) = 0.  fp32 -> first u32 == 0x00000000.
// bf16 -> first u32 = [bf16(0) | bf16(log 2)<<16] != 0.
// ---------------------------------------------------------------------------
__global__ void k_detect(const unsigned int* __restrict__ Alog_u32, int* __restrict__ flag) {
    *flag = (Alog_u32[0] != 0u) ? 1 : 0;
}

// ---------------------------------------------------------------------------
// Fused residual add + RMSNorm. One block per row (1024 cols, 256 thr x 4).
// first=1: residual = hidden_states input; else residual += hid (fp32).
// hout may alias hid (identity element mapping, read-before-write per thread).
// woff = element offset of this layer's norm weight.
// ---------------------------------------------------------------------------
__global__ __launch_bounds__(256) void k_addnorm(
    const float* __restrict__ hid, const void* __restrict__ hs,
    float* __restrict__ resid, float* __restrict__ hout,
    const void* __restrict__ w, size_t woff, int first,
    const int* __restrict__ flagp)
{
    const bool bf = (*flagp != 0);
    const int row = blockIdx.x;
    const int col = threadIdx.x * 4;
    const size_t base = (size_t)row * DMODEL + col;
    float r[4];
    if (first) {
        if (bf) {
            const ushort4 v = *(const ushort4*)((const unsigned short*)hs + base);
            r[0] = bf2f(v.x); r[1] = bf2f(v.y); r[2] = bf2f(v.z); r[3] = bf2f(v.w);
        } else {
            const float4 v = *(const float4*)((const float*)hs + base);
            r[0] = v.x; r[1] = v.y; r[2] = v.z; r[3] = v.w;
        }
    } else {
        const float4 hv = *(const float4*)(hid + base);
        const float4 rv = *(const float4*)(resid + base);
        r[0] = hv.x + rv.x; r[1] = hv.y + rv.y; r[2] = hv.z + rv.z; r[3] = hv.w + rv.w;
    }
    *(float4*)(resid + base) = make_float4(r[0], r[1], r[2], r[3]);
    float ss = r[0]*r[0] + r[1]*r[1] + r[2]*r[2] + r[3]*r[3];
    #pragma unroll
    for (int o = 32; o > 0; o >>= 1) ss += __shfl_down(ss, o);
    __shared__ float red[4];
    const int lane = threadIdx.x & 63, wv = threadIdx.x >> 6;
    if (lane == 0) red[wv] = ss;
    __syncthreads();
    const float total = red[0] + red[1] + red[2] + red[3];
    const float scale = rsqrtf(total * (1.0f / DMODEL) + 1e-5f);
    const float w0 = ldin(w, woff + col + 0, bf), w1 = ldin(w, woff + col + 1, bf);
    const float w2 = ldin(w, woff + col + 2, bf), w3 = ldin(w, woff + col + 3, bf);
    *(float4*)(hout + base) = make_float4(r[0] * scale * w0, r[1] * scale * w1,
                                          r[2] * scale * w2, r[3] * scale * w3);
}

// ---------------------------------------------------------------------------
// Generic NT GEMM: C[M,N] = A[M,K] (fp32, lda) * W[N,K]^T (input dtype, ldw).
// woff/boff = element offsets of this layer's weight/bias.
// mode 1: C = softplus(acc + bias[n])   (dt_proj epilogue)
// 64x64x16 tile, 256 threads, 4x4 micro-tile.
// ---------------------------------------------------------------------------
__global__ __launch_bounds__(256) void k_gemm_nt(
    const float* __restrict__ A, int lda,
    const void* __restrict__ W, size_t woff, int ldw,
    float* __restrict__ C, int ldc,
    int N, int K,
    const void* __restrict__ bias, size_t boff, int mode,
    const int* __restrict__ flagp)
{
    const bool bf = (*flagp != 0);
    __shared__ float As[16][65];
    __shared__ float Ws[16][65];
    const int tid = threadIdx.x;
    const int tx = tid & 15, ty = tid >> 4;
    const int m0 = blockIdx.x * 64;
    const int n0 = blockIdx.y * 64;
    const int lm = tid >> 2;          // 0..63
    const int lk = (tid & 3) * 4;     // 0,4,8,12
    float acc[4][4] = {{0.f, 0.f, 0.f, 0.f}, {0.f, 0.f, 0.f, 0.f},
                       {0.f, 0.f, 0.f, 0.f}, {0.f, 0.f, 0.f, 0.f}};
    for (int k0 = 0; k0 < K; k0 += 16) {
        const float4 av = *(const float4*)(A + (size_t)(m0 + lm) * lda + k0 + lk);
        As[lk + 0][lm] = av.x; As[lk + 1][lm] = av.y;
        As[lk + 2][lm] = av.z; As[lk + 3][lm] = av.w;
        const int n = n0 + lm;
        float w0 = 0.f, w1 = 0.f, w2 = 0.f, w3 = 0.f;
        if (n < N) {
            const size_t off = woff + (size_t)n * ldw + k0 + lk;
            if (bf) {
                const ushort4 wv = *(const ushort4*)((const unsigned short*)W + off);
                w0 = bf2f(wv.x); w1 = bf2f(wv.y); w2 = bf2f(wv.z); w3 = bf2f(wv.w);
            } else {
                const float4 wv = *(const float4*)((const float*)W + off);
                w0 = wv.x; w1 = wv.y; w2 = wv.z; w3 = wv.w;
            }
        }
        Ws[lk + 0][lm] = w0; Ws[lk + 1][lm] = w1;
        Ws[lk + 2][lm] = w2; Ws[lk + 3][lm] = w3;
        __syncthreads();
        #pragma unroll
        for (int kk = 0; kk < 16; ++kk) {
            float a[4], b[4];
            #pragma unroll
            for (int i = 0; i < 4; ++i) a[i] = As[kk][ty * 4 + i];
            #pragma unroll
            for (int j = 0; j < 4; ++j) b[j] = Ws[kk][tx * 4 + j];
            #pragma unroll
            for (int i = 0; i < 4; ++i)
                #pragma unroll
                for (int j = 0; j < 4; ++j)
                    acc[i][j] = fmaf(a[i], b[j], acc[i][j]);
        }
        __syncthreads();
    }
    #pragma unroll
    for (int i = 0; i < 4; ++i) {
        const int m = m0 + ty * 4 + i;
        #pragma unroll
        for (int j = 0; j < 4; ++j) {
            const int n = n0 + tx * 4 + j;
            if (n < N) {
                float v = acc[i][j];
                if (mode == 1) {
                    v += ldin(bias, boff + n, bf);
                    v = (v > 20.f) ? v : log1pf(__expf(v));
                }
                C[(size_t)m * ldc + n] = v;
            }
        }
    }
}

// ---------------------------------------------------------------------------
// Causal depthwise conv (k=4) + bias + SiLU.  u lives in xz cols [0, DINNER).
// ---------------------------------------------------------------------------
__global__ __launch_bounds__(256) void k_conv(
    const float* __restrict__ xz, const void* __restrict__ cw, size_t cwoff,
    const void* __restrict__ cb, size_t cboff, float* __restrict__ uc,
    const int* __restrict__ flagp)
{
    const bool bf = (*flagp != 0);
    const int idx = blockIdx.x * 256 + threadIdx.x;
    const int d = idx & (DINNER - 1);
    const int l = idx >> 11;
    const float w0 = ldin(cw, cwoff + d * 4 + 0, bf), w1 = ldin(cw, cwoff + d * 4 + 1, bf);
    const float w2 = ldin(cw, cwoff + d * 4 + 2, bf), w3 = ldin(cw, cwoff + d * 4 + 3, bf);
    float acc = ldin(cb, cboff + d, bf);
    if (l >= 3) acc = fmaf(xz[(size_t)(l - 3) * (2 * DINNER) + d], w0, acc);
    if (l >= 2) acc = fmaf(xz[(size_t)(l - 2) * (2 * DINNER) + d], w1, acc);
    if (l >= 1) acc = fmaf(xz[(size_t)(l - 1) * (2 * DINNER) + d], w2, acc);
    acc = fmaf(xz[(size_t)l * (2 * DINNER) + d], w3, acc);
    const float sig = 1.f / (1.f + __expf(-acc));
    uc[(size_t)l * DINNER + d] = acc * sig;
}

// ---------------------------------------------------------------------------
// Selective scan, one thread per channel d. h[16] in registers.
// B_t, C_t (xdbl cols 64..95) staged in LDS per 64-step chunk.
// Fused epilogue: y = (scan + uc*D) * silu(z).
// ---------------------------------------------------------------------------
__global__ __launch_bounds__(64) void k_scan(
    const float* __restrict__ delta, const float* __restrict__ uc,
    const float* __restrict__ xz, const float* __restrict__ xdbl,
    const void* __restrict__ Alog, size_t aoff,
    const void* __restrict__ Dp, size_t doff,
    float* __restrict__ y, const int* __restrict__ flagp)
{
    const bool bf = (*flagp != 0);
    __shared__ float sBC[64][32];
    const int d = blockIdx.x * 64 + threadIdx.x;
    float Arow[DSTATE];
    #pragma unroll
    for (int n = 0; n < DSTATE; ++n)
        Arow[n] = -__expf(ldin(Alog, aoff + (size_t)d * DSTATE + n, bf));
    const float Dv = ldin(Dp, doff + d, bf);
    float h[DSTATE];
    #pragma unroll
    for (int n = 0; n < DSTATE; ++n) h[n] = 0.f;

    for (int t0 = 0; t0 < L_SEQ; t0 += 64) {
        __syncthreads();
        #pragma unroll
        for (int r = 0; r < 32; ++r) {
            const int idx = r * 64 + threadIdx.x;   // 0..2047
            const int tt = idx >> 5, c = idx & 31;
            sBC[tt][c] = xdbl[(size_t)(t0 + tt) * XDIM + DTRANK + c];
        }
        __syncthreads();
        // prefetch first step of chunk
        float dcur = delta[(size_t)t0 * DINNER + d];
        float ucur = uc[(size_t)t0 * DINNER + d];
        float zcur = xz[(size_t)t0 * (2 * DINNER) + DINNER + d];
        for (int ti = 0; ti < 64; ++ti) {
            const int t = t0 + ti;
            float dnx = 0.f, unx = 0.f, znx = 0.f;
            if (ti < 63) {   // prefetch next step (hide HBM/L3 latency)
                dnx = delta[(size_t)(t + 1) * DINNER + d];
                unx = uc[(size_t)(t + 1) * DINNER + d];
                znx = xz[(size_t)(t + 1) * (2 * DINNER) + DINNER + d];
            }
            const float du = dcur * ucur;
            float dot = 0.f;
            #pragma unroll
            for (int n = 0; n < DSTATE; ++n) {
                const float dA = __expf(dcur * Arow[n]);
                h[n] = fmaf(dA, h[n], du * sBC[ti][n]);
                dot = fmaf(h[n], sBC[ti][DSTATE + n], dot);
            }
            const float sig = 1.f / (1.f + __expf(-zcur));
            y[(size_t)t * DINNER + d] = (dot + ucur * Dv) * (zcur * sig);
            dcur = dnx; ucur = unx; zcur = znx;
        }
    }
}

// ---------------------------------------------------------------------------
// Final: out = (hidden + residual), dtype per flag
// ---------------------------------------------------------------------------
__global__ __launch_bounds__(256) void k_final(
    const float* __restrict__ hh, const float* __restrict__ resid,
    void* __restrict__ out, const int* __restrict__ flagp)
{
    const bool bf = (*flagp != 0);
    const int i = (blockIdx.x * 256 + threadIdx.x) * 4;
    const float4 a = *(const float4*)(hh + i);
    const float4 b = *(const float4*)(resid + i);
    const float o0 = a.x + b.x, o1 = a.y + b.y, o2 = a.z + b.z, o3 = a.w + b.w;
    if (bf) {
        ushort4 o;
        o.x = f2bf(o0); o.y = f2bf(o1); o.z = f2bf(o2); o.w = f2bf(o3);
        *(ushort4*)((unsigned short*)out + i) = o;
    } else {
        *(float4*)((float*)out + i) = make_float4(o0, o1, o2, o3);
    }
}

extern "C" void kernel_launch(void* const* d_in, const int* in_sizes, int n_in,
                              void* d_out, int out_size, void* d_ws, size_t ws_size,
                              hipStream_t stream)
{
    const void* hs    = d_in[0];
    const void* normw = d_in[1];
    const void* ipw   = d_in[2];
    const void* cw    = d_in[3];
    const void* cb    = d_in[4];
    const void* xpw   = d_in[5];
    const void* dtw   = d_in[6];
    const void* dtb   = d_in[7];
    const void* Alog  = d_in[8];
    const void* Dp    = d_in[9];
    const void* opw   = d_in[10];

    // Workspace layout (fp32), total ~101.5 MiB + flag
    float* ws    = (float*)d_ws;
    float* resid = ws;                                      // L*DMODEL
    float* hh    = resid  + (size_t)L_SEQ * DMODEL;         // L*DMODEL
    float* xzb   = hh     + (size_t)L_SEQ * DMODEL;         // L*2*DINNER
    float* ucb   = xzb    + (size_t)L_SEQ * 2 * DINNER;     // L*DINNER
    float* xdblb = ucb    + (size_t)L_SEQ * DINNER;         // L*XDIM
    float* deltab= xdblb  + (size_t)L_SEQ * XDIM;           // L*DINNER
    float* yb    = deltab + (size_t)L_SEQ * DINNER;         // L*DINNER
    int*   flagp = (int*)(yb + (size_t)L_SEQ * DINNER);

    k_detect<<<1, 1, 0, stream>>>((const unsigned int*)Alog, flagp);

    for (int i = 0; i < NLAYER; ++i) {
        const size_t o_ipw = (size_t)i * 2 * DINNER * DMODEL;
        const size_t o_xpw = (size_t)i * XDIM * DINNER;
        const size_t o_dtw = (size_t)i * DINNER * DTRANK;
        const size_t o_opw = (size_t)i * DMODEL * DINNER;

        k_addnorm<<<L_SEQ, 256, 0, stream>>>(
            hh, hs, resid, hh, normw, (size_t)i * DMODEL, i == 0 ? 1 : 0, flagp);
        // in_proj: (L x DMODEL) @ (2*DINNER x DMODEL)^T -> xz (L x 4096)
        k_gemm_nt<<<dim3(L_SEQ / 64, (2 * DINNER) / 64), 256, 0, stream>>>(
            hh, DMODEL, ipw, o_ipw, DMODEL,
            xzb, 2 * DINNER, 2 * DINNER, DMODEL, nullptr, 0, 0, flagp);
        k_conv<<<(L_SEQ * DINNER) / 256, 256, 0, stream>>>(
            xzb, cw, (size_t)i * DINNER * DCONV, cb, (size_t)i * DINNER, ucb, flagp);
        // x_proj: (L x DINNER) @ (96 x DINNER)^T -> xdbl (L x 96)
        k_gemm_nt<<<dim3(L_SEQ / 64, 2), 256, 0, stream>>>(
            ucb, DINNER, xpw, o_xpw, DINNER,
            xdblb, XDIM, XDIM, DINNER, nullptr, 0, 0, flagp);
        // dt_proj + softplus: (L x 64) @ (DINNER x 64)^T -> delta (L x DINNER)
        k_gemm_nt<<<dim3(L_SEQ / 64, DINNER / 64), 256, 0, stream>>>(
            xdblb, XDIM, dtw, o_dtw, DTRANK,
            deltab, DINNER, DINNER, DTRANK, dtb, (size_t)i * DINNER, 1, flagp);
        k_scan<<<DINNER / 64, 64, 0, stream>>>(
            deltab, ucb, xzb, xdblb,
            Alog, (size_t)i * DINNER * DSTATE, Dp, (size_t)i * DINNER, yb, flagp);
        // out_proj: (L x DINNER) @ (DMODEL x DINNER)^T -> hidden (L x DMODEL)
        k_gemm_nt<<<dim3(L_SEQ / 64, DMODEL / 64), 256, 0, stream>>>(
            yb, DINNER, opw, o_opw, DINNER,
            hh, DMODEL, DMODEL, DINNER, nullptr, 0, 0, flagp);
    }
    k_final<<<(L_SEQ * DMODEL) / 1024, 256, 0, stream>>>(hh, resid, d_out, flagp);
}

// Round 3
// 3569.172 us; speedup vs baseline: 2.1252x; 2.1252x over previous
//
#include <hip/hip_runtime.h>
#include <hip/hip_bf16.h>

// Problem constants (from reference)
#define L_SEQ   2048
#define DMODEL  1024
#define DINNER  2048
#define DSTATE  16
#define DTRANK  64
#define DCONV   4
#define NLAYER  4
#define XDIM    96   // DTRANK + 2*DSTATE
#define CHUNK   64
#define NCHUNK  (L_SEQ / CHUNK)   // 32

__device__ __forceinline__ float bf2f(unsigned short u) {
    union { unsigned int i; float f; } v; v.i = ((unsigned int)u) << 16; return v.f;
}
__device__ __forceinline__ unsigned short f2bf(float f) {
    union { float f; unsigned int i; } v; v.f = f;
    unsigned int x = v.i;
    unsigned int r = (x + 0x7fffu + ((x >> 16) & 1u)) >> 16;  // RTNE
    return (unsigned short)r;
}
// scalar load of input element idx, dtype selected by bf flag
__device__ __forceinline__ float ldin(const void* p, size_t idx, bool bf) {
    return bf ? bf2f(((const unsigned short*)p)[idx]) : ((const float*)p)[idx];
}

// ---------------------------------------------------------------------------
// Dtype detector: A_log[0] = log(1) = 0.  fp32 -> first u32 == 0x00000000.
// bf16 -> first u32 = [bf16(0) | bf16(log 2)<<16] != 0.
// ---------------------------------------------------------------------------
__global__ void k_detect(const unsigned int* __restrict__ Alog_u32, int* __restrict__ flag) {
    *flag = (Alog_u32[0] != 0u) ? 1 : 0;
}

// ---------------------------------------------------------------------------
// Fused residual add + RMSNorm. One block per row (1024 cols, 256 thr x 4).
// ---------------------------------------------------------------------------
__global__ __launch_bounds__(256) void k_addnorm(
    const float* __restrict__ hid, const void* __restrict__ hs,
    float* __restrict__ resid, float* __restrict__ hout,
    const void* __restrict__ w, size_t woff, int first,
    const int* __restrict__ flagp)
{
    const bool bf = (*flagp != 0);
    const int row = blockIdx.x;
    const int col = threadIdx.x * 4;
    const size_t base = (size_t)row * DMODEL + col;
    float r[4];
    if (first) {
        if (bf) {
            const ushort4 v = *(const ushort4*)((const unsigned short*)hs + base);
            r[0] = bf2f(v.x); r[1] = bf2f(v.y); r[2] = bf2f(v.z); r[3] = bf2f(v.w);
        } else {
            const float4 v = *(const float4*)((const float*)hs + base);
            r[0] = v.x; r[1] = v.y; r[2] = v.z; r[3] = v.w;
        }
    } else {
        const float4 hv = *(const float4*)(hid + base);
        const float4 rv = *(const float4*)(resid + base);
        r[0] = hv.x + rv.x; r[1] = hv.y + rv.y; r[2] = hv.z + rv.z; r[3] = hv.w + rv.w;
    }
    *(float4*)(resid + base) = make_float4(r[0], r[1], r[2], r[3]);
    float ss = r[0]*r[0] + r[1]*r[1] + r[2]*r[2] + r[3]*r[3];
    #pragma unroll
    for (int o = 32; o > 0; o >>= 1) ss += __shfl_down(ss, o);
    __shared__ float red[4];
    const int lane = threadIdx.x & 63, wv = threadIdx.x >> 6;
    if (lane == 0) red[wv] = ss;
    __syncthreads();
    const float total = red[0] + red[1] + red[2] + red[3];
    const float scale = rsqrtf(total * (1.0f / DMODEL) + 1e-5f);
    const float w0 = ldin(w, woff + col + 0, bf), w1 = ldin(w, woff + col + 1, bf);
    const float w2 = ldin(w, woff + col + 2, bf), w3 = ldin(w, woff + col + 3, bf);
    *(float4*)(hout + base) = make_float4(r[0] * scale * w0, r[1] * scale * w1,
                                          r[2] * scale * w2, r[3] * scale * w3);
}

// ---------------------------------------------------------------------------
// Generic NT GEMM: C[M,N] = A[M,K] (fp32, lda) * W[N,K]^T (input dtype, ldw).
// mode 1: C = softplus(acc + bias[n])   (dt_proj epilogue)
// 64x64x16 tile, 256 threads, 4x4 micro-tile.
// ---------------------------------------------------------------------------
__global__ __launch_bounds__(256) void k_gemm_nt(
    const float* __restrict__ A, int lda,
    const void* __restrict__ W, size_t woff, int ldw,
    float* __restrict__ C, int ldc,
    int N, int K,
    const void* __restrict__ bias, size_t boff, int mode,
    const int* __restrict__ flagp)
{
    const bool bf = (*flagp != 0);
    __shared__ float As[16][65];
    __shared__ float Ws[16][65];
    const int tid = threadIdx.x;
    const int tx = tid & 15, ty = tid >> 4;
    const int m0 = blockIdx.x * 64;
    const int n0 = blockIdx.y * 64;
    const int lm = tid >> 2;          // 0..63
    const int lk = (tid & 3) * 4;     // 0,4,8,12
    float acc[4][4] = {{0.f, 0.f, 0.f, 0.f}, {0.f, 0.f, 0.f, 0.f},
                       {0.f, 0.f, 0.f, 0.f}, {0.f, 0.f, 0.f, 0.f}};
    for (int k0 = 0; k0 < K; k0 += 16) {
        const float4 av = *(const float4*)(A + (size_t)(m0 + lm) * lda + k0 + lk);
        As[lk + 0][lm] = av.x; As[lk + 1][lm] = av.y;
        As[lk + 2][lm] = av.z; As[lk + 3][lm] = av.w;
        const int n = n0 + lm;
        float w0 = 0.f, w1 = 0.f, w2 = 0.f, w3 = 0.f;
        if (n < N) {
            const size_t off = woff + (size_t)n * ldw + k0 + lk;
            if (bf) {
                const ushort4 wv = *(const ushort4*)((const unsigned short*)W + off);
                w0 = bf2f(wv.x); w1 = bf2f(wv.y); w2 = bf2f(wv.z); w3 = bf2f(wv.w);
            } else {
                const float4 wv = *(const float4*)((const float*)W + off);
                w0 = wv.x; w1 = wv.y; w2 = wv.z; w3 = wv.w;
            }
        }
        Ws[lk + 0][lm] = w0; Ws[lk + 1][lm] = w1;
        Ws[lk + 2][lm] = w2; Ws[lk + 3][lm] = w3;
        __syncthreads();
        #pragma unroll
        for (int kk = 0; kk < 16; ++kk) {
            float a[4], b[4];
            #pragma unroll
            for (int i = 0; i < 4; ++i) a[i] = As[kk][ty * 4 + i];
            #pragma unroll
            for (int j = 0; j < 4; ++j) b[j] = Ws[kk][tx * 4 + j];
            #pragma unroll
            for (int i = 0; i < 4; ++i)
                #pragma unroll
                for (int j = 0; j < 4; ++j)
                    acc[i][j] = fmaf(a[i], b[j], acc[i][j]);
        }
        __syncthreads();
    }
    #pragma unroll
    for (int i = 0; i < 4; ++i) {
        const int m = m0 + ty * 4 + i;
        #pragma unroll
        for (int j = 0; j < 4; ++j) {
            const int n = n0 + tx * 4 + j;
            if (n < N) {
                float v = acc[i][j];
                if (mode == 1) {
                    v += ldin(bias, boff + n, bf);
                    v = (v > 20.f) ? v : log1pf(__expf(v));
                }
                C[(size_t)m * ldc + n] = v;
            }
        }
    }
}

// ---------------------------------------------------------------------------
// Causal depthwise conv (k=4) + bias + SiLU.  u lives in xz cols [0, DINNER).
// ---------------------------------------------------------------------------
__global__ __launch_bounds__(256) void k_conv(
    const float* __restrict__ xz, const void* __restrict__ cw, size_t cwoff,
    const void* __restrict__ cb, size_t cboff, float* __restrict__ uc,
    const int* __restrict__ flagp)
{
    const bool bf = (*flagp != 0);
    const int idx = blockIdx.x * 256 + threadIdx.x;
    const int d = idx & (DINNER - 1);
    const int l = idx >> 11;
    const float w0 = ldin(cw, cwoff + d * 4 + 0, bf), w1 = ldin(cw, cwoff + d * 4 + 1, bf);
    const float w2 = ldin(cw, cwoff + d * 4 + 2, bf), w3 = ldin(cw, cwoff + d * 4 + 3, bf);
    float acc = ldin(cb, cboff + d, bf);
    if (l >= 3) acc = fmaf(xz[(size_t)(l - 3) * (2 * DINNER) + d], w0, acc);
    if (l >= 2) acc = fmaf(xz[(size_t)(l - 2) * (2 * DINNER) + d], w1, acc);
    if (l >= 1) acc = fmaf(xz[(size_t)(l - 1) * (2 * DINNER) + d], w2, acc);
    acc = fmaf(xz[(size_t)l * (2 * DINNER) + d], w3, acc);
    const float sig = 1.f / (1.f + __expf(-acc));
    uc[(size_t)l * DINNER + d] = acc * sig;
}

// ---------------------------------------------------------------------------
// Chunked selective scan, pass 1: per (channel-block, chunk) local scan from
// h=0. Writes hloc[c][d][0..15] and sdelta[c][d] = sum of delta over chunk.
// (Chunk decay product = exp(A[n] * sdelta) since A is time-invariant.)
// ---------------------------------------------------------------------------
__global__ __launch_bounds__(128) void k_scan1(
    const float* __restrict__ delta, const float* __restrict__ uc,
    const float* __restrict__ xdbl,
    const void* __restrict__ Alog, size_t aoff,
    float* __restrict__ hloc, float* __restrict__ sdelta,
    const int* __restrict__ flagp)
{
    const bool bf = (*flagp != 0);
    __shared__ float sB[CHUNK][DSTATE];
    const int d = blockIdx.x * 128 + threadIdx.x;
    const int c = blockIdx.y;
    const int t0 = c * CHUNK;
    float Arow[DSTATE];
    #pragma unroll
    for (int n = 0; n < DSTATE; ++n)
        Arow[n] = -__expf(ldin(Alog, aoff + (size_t)d * DSTATE + n, bf));
    // stage B for the chunk: CHUNK*16 = 1024 floats, 128 threads x 8
    #pragma unroll
    for (int r = 0; r < 8; ++r) {
        const int idx = r * 128 + threadIdx.x;
        const int tt = idx >> 4, n = idx & 15;
        sB[tt][n] = xdbl[(size_t)(t0 + tt) * XDIM + DTRANK + n];
    }
    __syncthreads();
    float h[DSTATE];
    #pragma unroll
    for (int n = 0; n < DSTATE; ++n) h[n] = 0.f;
    float sd = 0.f;
    for (int ti = 0; ti < CHUNK; ++ti) {
        const int t = t0 + ti;
        const float d_t = delta[(size_t)t * DINNER + d];
        const float u_t = uc[(size_t)t * DINNER + d];
        sd += d_t;
        const float du = d_t * u_t;
        #pragma unroll
        for (int n = 0; n < DSTATE; ++n) {
            const float dA = __expf(d_t * Arow[n]);
            h[n] = fmaf(dA, h[n], du * sB[ti][n]);
        }
    }
    float* hp = hloc + ((size_t)c * DINNER + d) * DSTATE;
    #pragma unroll
    for (int n = 0; n < DSTATE; n += 4)
        *(float4*)(hp + n) = make_float4(h[n], h[n + 1], h[n + 2], h[n + 3]);
    sdelta[(size_t)c * DINNER + d] = sd;
}

// ---------------------------------------------------------------------------
// Pass 2: per (d,n), sequential scan over the 32 chunk states. In-place:
// after this kernel, hloc[c] holds the state ENTERING chunk c (Hin[c]).
//   carry_0 = 0; loop c: tmp = hloc[c]; hloc[c] = carry;
//                        carry = exp(A*sdelta[c]) * carry + tmp
// ---------------------------------------------------------------------------
__global__ __launch_bounds__(256) void k_scan2(
    float* __restrict__ hloc, const float* __restrict__ sdelta,
    const void* __restrict__ Alog, size_t aoff,
    const int* __restrict__ flagp)
{
    const bool bf = (*flagp != 0);
    const int gid = blockIdx.x * 256 + threadIdx.x;   // 0 .. DINNER*DSTATE-1
    const int d = gid >> 4, n = gid & 15;
    const float A = -__expf(ldin(Alog, aoff + (size_t)d * DSTATE + n, bf));
    float carry = 0.f;
    for (int c = 0; c < NCHUNK; ++c) {
        const size_t idx = ((size_t)c * DINNER + d) * DSTATE + n;
        const float tmp = hloc[idx];
        hloc[idx] = carry;
        const float P = __expf(A * sdelta[(size_t)c * DINNER + d]);
        carry = fmaf(P, carry, tmp);
    }
}

// ---------------------------------------------------------------------------
// Pass 3: re-run local scan seeded with Hin[c] (= hloc after pass 2),
// compute y with full epilogue: y = (C.h + uc*D) * silu(z).
// ---------------------------------------------------------------------------
__global__ __launch_bounds__(128) void k_scan3(
    const float* __restrict__ delta, const float* __restrict__ uc,
    const float* __restrict__ xz, const float* __restrict__ xdbl,
    const void* __restrict__ Alog, size_t aoff,
    const void* __restrict__ Dp, size_t doff,
    const float* __restrict__ hin, float* __restrict__ y,
    const int* __restrict__ flagp)
{
    const bool bf = (*flagp != 0);
    __shared__ float sBC[CHUNK][2 * DSTATE];
    const int d = blockIdx.x * 128 + threadIdx.x;
    const int c = blockIdx.y;
    const int t0 = c * CHUNK;
    float Arow[DSTATE];
    #pragma unroll
    for (int n = 0; n < DSTATE; ++n)
        Arow[n] = -__expf(ldin(Alog, aoff + (size_t)d * DSTATE + n, bf));
    const float Dv = ldin(Dp, doff + d, bf);
    // stage B and C: CHUNK*32 = 2048 floats, 128 threads x 16
    #pragma unroll
    for (int r = 0; r < 16; ++r) {
        const int idx = r * 128 + threadIdx.x;
        const int tt = idx >> 5, n = idx & 31;
        sBC[tt][n] = xdbl[(size_t)(t0 + tt) * XDIM + DTRANK + n];
    }
    __syncthreads();
    float h[DSTATE];
    const float* hp = hin + ((size_t)c * DINNER + d) * DSTATE;
    #pragma unroll
    for (int n = 0; n < DSTATE; n += 4) {
        const float4 v = *(const float4*)(hp + n);
        h[n] = v.x; h[n + 1] = v.y; h[n + 2] = v.z; h[n + 3] = v.w;
    }
    for (int ti = 0; ti < CHUNK; ++ti) {
        const int t = t0 + ti;
        const float d_t = delta[(size_t)t * DINNER + d];
        const float u_t = uc[(size_t)t * DINNER + d];
        const float z_t = xz[(size_t)t * (2 * DINNER) + DINNER + d];
        const float du = d_t * u_t;
        float dot = 0.f;
        #pragma unroll
        for (int n = 0; n < DSTATE; ++n) {
            const float dA = __expf(d_t * Arow[n]);
            h[n] = fmaf(dA, h[n], du * sBC[ti][n]);
            dot = fmaf(h[n], sBC[ti][DSTATE + n], dot);
        }
        const float sig = 1.f / (1.f + __expf(-z_t));
        y[(size_t)t * DINNER + d] = (dot + u_t * Dv) * (z_t * sig);
    }
}

// ---------------------------------------------------------------------------
// Final: out = (hidden + residual), dtype per flag
// ---------------------------------------------------------------------------
__global__ __launch_bounds__(256) void k_final(
    const float* __restrict__ hh, const float* __restrict__ resid,
    void* __restrict__ out, const int* __restrict__ flagp)
{
    const bool bf = (*flagp != 0);
    const int i = (blockIdx.x * 256 + threadIdx.x) * 4;
    const float4 a = *(const float4*)(hh + i);
    const float4 b = *(const float4*)(resid + i);
    const float o0 = a.x + b.x, o1 = a.y + b.y, o2 = a.z + b.z, o3 = a.w + b.w;
    if (bf) {
        ushort4 o;
        o.x = f2bf(o0); o.y = f2bf(o1); o.z = f2bf(o2); o.w = f2bf(o3);
        *(ushort4*)((unsigned short*)out + i) = o;
    } else {
        *(float4*)((float*)out + i) = make_float4(o0, o1, o2, o3);
    }
}

extern "C" void kernel_launch(void* const* d_in, const int* in_sizes, int n_in,
                              void* d_out, int out_size, void* d_ws, size_t ws_size,
                              hipStream_t stream)
{
    const void* hs    = d_in[0];
    const void* normw = d_in[1];
    const void* ipw   = d_in[2];
    const void* cw    = d_in[3];
    const void* cb    = d_in[4];
    const void* xpw   = d_in[5];
    const void* dtw   = d_in[6];
    const void* dtb   = d_in[7];
    const void* Alog  = d_in[8];
    const void* Dp    = d_in[9];
    const void* opw   = d_in[10];

    // Workspace layout (fp32), total ~97 MiB + flag
    float* ws    = (float*)d_ws;
    float* resid = ws;                                      // L*DMODEL
    float* hh    = resid  + (size_t)L_SEQ * DMODEL;         // L*DMODEL
    float* xzb   = hh     + (size_t)L_SEQ * DMODEL;         // L*2*DINNER
    float* ucb   = xzb    + (size_t)L_SEQ * 2 * DINNER;     // L*DINNER
    float* xdblb = ucb    + (size_t)L_SEQ * DINNER;         // L*XDIM
    float* deltab= xdblb  + (size_t)L_SEQ * XDIM;           // L*DINNER
    float* yb    = deltab + (size_t)L_SEQ * DINNER;         // L*DINNER
    int*   flagp = (int*)(yb + (size_t)L_SEQ * DINNER);

    // Scan scratch lives inside hh (dead between in_proj and out_proj):
    // hloc: NCHUNK*DINNER*DSTATE = 1,048,576 floats; sdelta: 65,536 floats.
    // Total 1,114,112 <= hh's 2,097,152.
    float* hlocb   = hh;
    float* sdeltab = hh + (size_t)NCHUNK * DINNER * DSTATE;

    k_detect<<<1, 1, 0, stream>>>((const unsigned int*)Alog, flagp);

    for (int i = 0; i < NLAYER; ++i) {
        const size_t o_ipw = (size_t)i * 2 * DINNER * DMODEL;
        const size_t o_xpw = (size_t)i * XDIM * DINNER;
        const size_t o_dtw = (size_t)i * DINNER * DTRANK;
        const size_t o_opw = (size_t)i * DMODEL * DINNER;
        const size_t o_al  = (size_t)i * DINNER * DSTATE;

        k_addnorm<<<L_SEQ, 256, 0, stream>>>(
            hh, hs, resid, hh, normw, (size_t)i * DMODEL, i == 0 ? 1 : 0, flagp);
        // in_proj: (L x DMODEL) @ (2*DINNER x DMODEL)^T -> xz (L x 4096)
        k_gemm_nt<<<dim3(L_SEQ / 64, (2 * DINNER) / 64), 256, 0, stream>>>(
            hh, DMODEL, ipw, o_ipw, DMODEL,
            xzb, 2 * DINNER, 2 * DINNER, DMODEL, nullptr, 0, 0, flagp);
        k_conv<<<(L_SEQ * DINNER) / 256, 256, 0, stream>>>(
            xzb, cw, (size_t)i * DINNER * DCONV, cb, (size_t)i * DINNER, ucb, flagp);
        // x_proj: (L x DINNER) @ (96 x DINNER)^T -> xdbl (L x 96)
        k_gemm_nt<<<dim3(L_SEQ / 64, 2), 256, 0, stream>>>(
            ucb, DINNER, xpw, o_xpw, DINNER,
            xdblb, XDIM, XDIM, DINNER, nullptr, 0, 0, flagp);
        // dt_proj + softplus: (L x 64) @ (DINNER x 64)^T -> delta (L x DINNER)
        k_gemm_nt<<<dim3(L_SEQ / 64, DINNER / 64), 256, 0, stream>>>(
            xdblb, XDIM, dtw, o_dtw, DTRANK,
            deltab, DINNER, DINNER, DTRANK, dtb, (size_t)i * DINNER, 1, flagp);
        // chunk-parallel selective scan (3 passes); scratch overlays hh
        k_scan1<<<dim3(DINNER / 128, NCHUNK), 128, 0, stream>>>(
            deltab, ucb, xdblb, Alog, o_al, hlocb, sdeltab, flagp);
        k_scan2<<<(DINNER * DSTATE) / 256, 256, 0, stream>>>(
            hlocb, sdeltab, Alog, o_al, flagp);
        k_scan3<<<dim3(DINNER / 128, NCHUNK), 128, 0, stream>>>(
            deltab, ucb, xzb, xdblb, Alog, o_al, Dp, (size_t)i * DINNER,
            hlocb, yb, flagp);
        // out_proj: (L x DINNER) @ (DMODEL x DINNER)^T -> hidden (L x DMODEL)
        k_gemm_nt<<<dim3(L_SEQ / 64, DMODEL / 64), 256, 0, stream>>>(
            yb, DINNER, opw, o_opw, DINNER,
            hh, DMODEL, DMODEL, DINNER, nullptr, 0, 0, flagp);
    }
    k_final<<<(L_SEQ * DMODEL) / 1024, 256, 0, stream>>>(hh, resid, d_out, flagp);
}

// Round 4
// 1375.127 us; speedup vs baseline: 5.5160x; 2.5955x over previous
//
#include <hip/hip_runtime.h>
#include <hip/hip_bf16.h>

// Problem constants (from reference)
#define L_SEQ   2048
#define DMODEL  1024
#define DINNER  2048
#define DSTATE  16
#define DTRANK  64
#define DCONV   4
#define NLAYER  4
#define XDIM    96   // DTRANK + 2*DSTATE
#define CHUNK   64
#define NCHUNK  (L_SEQ / CHUNK)   // 32
#define KSPLIT  8                 // x_proj split-K factor

typedef __attribute__((ext_vector_type(8))) short bf16x8;
typedef __attribute__((ext_vector_type(4))) float f32x4;

__device__ __forceinline__ float bf2f(unsigned short u) {
    union { unsigned int i; float f; } v; v.i = ((unsigned int)u) << 16; return v.f;
}
__device__ __forceinline__ unsigned short f2bf(float f) {
    union { float f; unsigned int i; } v; v.f = f;
    unsigned int x = v.i;
    unsigned int r = (x + 0x7fffu + ((x >> 16) & 1u)) >> 16;  // RTNE
    return (unsigned short)r;
}
// pack two fp32 -> two bf16 in a u32 (round-to-nearest, half-up; staging only)
__device__ __forceinline__ unsigned int pk2(float a, float b) {
    union { float f; unsigned int i; } ua, ub; ua.f = a; ub.f = b;
    const unsigned int x = (ua.i + 0x8000u) >> 16;
    const unsigned int y = (ub.i + 0x8000u) >> 16;
    return x | (y << 16);
}
// scalar load of input element idx, dtype selected by bf flag
__device__ __forceinline__ float ldin(const void* p, size_t idx, bool bf) {
    return bf ? bf2f(((const unsigned short*)p)[idx]) : ((const float*)p)[idx];
}

// ---------------------------------------------------------------------------
// Dtype detector: A_log[0] = log(1) = 0.  fp32 -> first u32 == 0x00000000.
// ---------------------------------------------------------------------------
__global__ void k_detect(const unsigned int* __restrict__ Alog_u32, int* __restrict__ flag) {
    *flag = (Alog_u32[0] != 0u) ? 1 : 0;
}

// ---------------------------------------------------------------------------
// Fused residual add + RMSNorm. One block per row (1024 cols, 256 thr x 4).
// Writes resid (fp32) and hnorm (bf16 — feeds in_proj MFMA A-operand).
// ---------------------------------------------------------------------------
__global__ __launch_bounds__(256) void k_addnorm(
    const float* __restrict__ hid, const void* __restrict__ hs,
    float* __restrict__ resid, unsigned short* __restrict__ hnorm,
    const void* __restrict__ w, size_t woff, int first,
    const int* __restrict__ flagp)
{
    const bool bf = (*flagp != 0);
    const int row = blockIdx.x;
    const int col = threadIdx.x * 4;
    const size_t base = (size_t)row * DMODEL + col;
    float r[4];
    if (first) {
        if (bf) {
            const ushort4 v = *(const ushort4*)((const unsigned short*)hs + base);
            r[0] = bf2f(v.x); r[1] = bf2f(v.y); r[2] = bf2f(v.z); r[3] = bf2f(v.w);
        } else {
            const float4 v = *(const float4*)((const float*)hs + base);
            r[0] = v.x; r[1] = v.y; r[2] = v.z; r[3] = v.w;
        }
    } else {
        const float4 hv = *(const float4*)(hid + base);
        const float4 rv = *(const float4*)(resid + base);
        r[0] = hv.x + rv.x; r[1] = hv.y + rv.y; r[2] = hv.z + rv.z; r[3] = hv.w + rv.w;
    }
    *(float4*)(resid + base) = make_float4(r[0], r[1], r[2], r[3]);
    float ss = r[0]*r[0] + r[1]*r[1] + r[2]*r[2] + r[3]*r[3];
    #pragma unroll
    for (int o = 32; o > 0; o >>= 1) ss += __shfl_down(ss, o);
    __shared__ float red[4];
    const int lane = threadIdx.x & 63, wv = threadIdx.x >> 6;
    if (lane == 0) red[wv] = ss;
    __syncthreads();
    const float total = red[0] + red[1] + red[2] + red[3];
    const float scale = rsqrtf(total * (1.0f / DMODEL) + 1e-5f);
    const float w0 = ldin(w, woff + col + 0, bf), w1 = ldin(w, woff + col + 1, bf);
    const float w2 = ldin(w, woff + col + 2, bf), w3 = ldin(w, woff + col + 3, bf);
    ushort4 o;
    o.x = f2bf(r[0] * scale * w0); o.y = f2bf(r[1] * scale * w1);
    o.z = f2bf(r[2] * scale * w2); o.w = f2bf(r[3] * scale * w3);
    *(ushort4*)(hnorm + base) = o;
}

// ---------------------------------------------------------------------------
// MFMA NT GEMM: C[M,N] = A[M,K]_bf16 * W[N,K]^T (input dtype).
// 128x128 tile, 256 thr (2x2 waves of 64x64), BK=32, mfma_f32_16x16x32_bf16.
// LDS row stride 40 bf16 (80 B): ds_read_b128-legal, <=2-way read conflicts.
// blockIdx.z = split-K slice (k0 = z*Kslice, C += z*czstride).
// mode 1: C = softplus(acc + bias[n]).
// ---------------------------------------------------------------------------
__global__ __launch_bounds__(256) void k_gemm_mfma(
    const unsigned short* __restrict__ A, int lda,
    const void* __restrict__ W, size_t woff, int ldw,
    float* __restrict__ C, int ldc, size_t czstride,
    int N, int Kslice,
    const void* __restrict__ bias, size_t boff, int mode,
    const int* __restrict__ flagp)
{
    const bool bf = (*flagp != 0);
    __shared__ unsigned short lA[128 * 40];
    __shared__ unsigned short lB[128 * 40];
    const int tid = threadIdx.x;
    const int m0 = blockIdx.x * 128;
    const int n0 = blockIdx.y * 128;
    const int k0 = blockIdx.z * Kslice;
    float* Cz = C + (size_t)blockIdx.z * czstride;

    const int w    = tid >> 6;            // wave 0..3
    const int lane = tid & 63;
    const int wm = (w >> 1) * 64, wn = (w & 1) * 64;
    const int m16 = lane & 15, kg = lane >> 4;

    const int sr = tid >> 1;              // staging row 0..127
    const int sh = (tid & 1) * 16;        // k offset 0 / 16

    f32x4 acc[4][4];
    #pragma unroll
    for (int i = 0; i < 4; ++i)
        #pragma unroll
        for (int j = 0; j < 4; ++j)
            acc[i][j] = (f32x4){0.f, 0.f, 0.f, 0.f};

    for (int kb = 0; kb < Kslice; kb += 32) {
        const int kk = k0 + kb + sh;
        {   // stage A (always bf16): 16 bf16 = 32 B per thread
            const uint4* src = (const uint4*)(A + (size_t)(m0 + sr) * lda + kk);
            const uint4 v0 = src[0];
            const uint4 v1 = src[1];
            *(uint4*)&lA[sr * 40 + sh]     = v0;
            *(uint4*)&lA[sr * 40 + sh + 8] = v1;
        }
        {   // stage B (weights, dtype-branched)
            const int n = n0 + sr;
            uint4 v0 = {0u, 0u, 0u, 0u}, v1 = {0u, 0u, 0u, 0u};
            if (n < N) {
                if (bf) {
                    const uint4* src = (const uint4*)((const unsigned short*)W + woff + (size_t)n * ldw + kk);
                    v0 = src[0]; v1 = src[1];
                } else {
                    const float4* src = (const float4*)((const float*)W + woff + (size_t)n * ldw + kk);
                    const float4 f0 = src[0], f1 = src[1], f2 = src[2], f3 = src[3];
                    v0.x = pk2(f0.x, f0.y); v0.y = pk2(f0.z, f0.w);
                    v0.z = pk2(f1.x, f1.y); v0.w = pk2(f1.z, f1.w);
                    v1.x = pk2(f2.x, f2.y); v1.y = pk2(f2.z, f2.w);
                    v1.z = pk2(f3.x, f3.y); v1.w = pk2(f3.z, f3.w);
                }
            }
            *(uint4*)&lB[sr * 40 + sh]     = v0;
            *(uint4*)&lB[sr * 40 + sh + 8] = v1;
        }
        __syncthreads();
        bf16x8 af[4], bfr[4];
        #pragma unroll
        for (int i = 0; i < 4; ++i)
            af[i] = *(const bf16x8*)&lA[(wm + i * 16 + m16) * 40 + kg * 8];
        #pragma unroll
        for (int j = 0; j < 4; ++j)
            bfr[j] = *(const bf16x8*)&lB[(wn + j * 16 + m16) * 40 + kg * 8];
        #pragma unroll
        for (int i = 0; i < 4; ++i)
            #pragma unroll
            for (int j = 0; j < 4; ++j)
                acc[i][j] = __builtin_amdgcn_mfma_f32_16x16x32_bf16(af[i], bfr[j], acc[i][j], 0, 0, 0);
        __syncthreads();
    }
    // epilogue: D row=(lane>>4)*4+reg, col=lane&15  [verified gfx950 layout]
    const int rowb = (lane >> 4) * 4;
    #pragma unroll
    for (int j = 0; j < 4; ++j) {
        const int col = n0 + wn + j * 16 + m16;
        if (col < N) {
            float bv = 0.f;
            if (mode == 1) bv = ldin(bias, boff + col, bf);
            #pragma unroll
            for (int i = 0; i < 4; ++i) {
                #pragma unroll
                for (int r = 0; r < 4; ++r) {
                    const int row = m0 + wm + i * 16 + rowb + r;
                    float v = acc[i][j][r];
                    if (mode == 1) { v += bv; v = (v > 20.f) ? v : log1pf(__expf(v)); }
                    Cz[(size_t)row * ldc + col] = v;
                }
            }
        }
    }
}

// ---------------------------------------------------------------------------
// Causal depthwise conv (k=4) + bias + SiLU. Dual write: fp32 (scan) + bf16
// (x_proj A-operand).
// ---------------------------------------------------------------------------
__global__ __launch_bounds__(256) void k_conv(
    const float* __restrict__ xz, const void* __restrict__ cw, size_t cwoff,
    const void* __restrict__ cb, size_t cboff,
    float* __restrict__ uc, unsigned short* __restrict__ uch,
    const int* __restrict__ flagp)
{
    const bool bf = (*flagp != 0);
    const int idx = blockIdx.x * 256 + threadIdx.x;
    const int d = idx & (DINNER - 1);
    const int l = idx >> 11;
    const float w0 = ldin(cw, cwoff + d * 4 + 0, bf), w1 = ldin(cw, cwoff + d * 4 + 1, bf);
    const float w2 = ldin(cw, cwoff + d * 4 + 2, bf), w3 = ldin(cw, cwoff + d * 4 + 3, bf);
    float acc = ldin(cb, cboff + d, bf);
    if (l >= 3) acc = fmaf(xz[(size_t)(l - 3) * (2 * DINNER) + d], w0, acc);
    if (l >= 2) acc = fmaf(xz[(size_t)(l - 2) * (2 * DINNER) + d], w1, acc);
    if (l >= 1) acc = fmaf(xz[(size_t)(l - 1) * (2 * DINNER) + d], w2, acc);
    acc = fmaf(xz[(size_t)l * (2 * DINNER) + d], w3, acc);
    const float sig = 1.f / (1.f + __expf(-acc));
    const float v = acc * sig;
    uc[(size_t)l * DINNER + d] = v;
    uch[(size_t)l * DINNER + d] = f2bf(v);
}

// ---------------------------------------------------------------------------
// x_proj split-K reduce: xdbl = sum of KSPLIT partials; dual write fp32+bf16.
// ---------------------------------------------------------------------------
__global__ __launch_bounds__(256) void k_reduce(
    const float* __restrict__ parts, float* __restrict__ xdbl,
    unsigned short* __restrict__ xdbl_bf)
{
    const int idx = blockIdx.x * 256 + threadIdx.x;   // 0 .. L*XDIM-1
    float s = 0.f;
    #pragma unroll
    for (int z = 0; z < KSPLIT; ++z)
        s += parts[(size_t)z * L_SEQ * XDIM + idx];
    xdbl[idx] = s;
    xdbl_bf[idx] = f2bf(s);
}

// ---------------------------------------------------------------------------
// Chunked selective scan, pass 1: local scan from h=0 per (channels, chunk).
// ---------------------------------------------------------------------------
__global__ __launch_bounds__(128) void k_scan1(
    const float* __restrict__ delta, const float* __restrict__ uc,
    const float* __restrict__ xdbl,
    const void* __restrict__ Alog, size_t aoff,
    float* __restrict__ hloc, float* __restrict__ sdelta,
    const int* __restrict__ flagp)
{
    const bool bf = (*flagp != 0);
    __shared__ float sB[CHUNK][DSTATE];
    const int d = blockIdx.x * 128 + threadIdx.x;
    const int c = blockIdx.y;
    const int t0 = c * CHUNK;
    float Arow[DSTATE];
    #pragma unroll
    for (int n = 0; n < DSTATE; ++n)
        Arow[n] = -__expf(ldin(Alog, aoff + (size_t)d * DSTATE + n, bf));
    #pragma unroll
    for (int r = 0; r < 8; ++r) {
        const int idx = r * 128 + threadIdx.x;
        const int tt = idx >> 4, n = idx & 15;
        sB[tt][n] = xdbl[(size_t)(t0 + tt) * XDIM + DTRANK + n];
    }
    __syncthreads();
    float h[DSTATE];
    #pragma unroll
    for (int n = 0; n < DSTATE; ++n) h[n] = 0.f;
    float sd = 0.f;
    for (int ti = 0; ti < CHUNK; ++ti) {
        const int t = t0 + ti;
        const float d_t = delta[(size_t)t * DINNER + d];
        const float u_t = uc[(size_t)t * DINNER + d];
        sd += d_t;
        const float du = d_t * u_t;
        #pragma unroll
        for (int n = 0; n < DSTATE; ++n) {
            const float dA = __expf(d_t * Arow[n]);
            h[n] = fmaf(dA, h[n], du * sB[ti][n]);
        }
    }
    float* hp = hloc + ((size_t)c * DINNER + d) * DSTATE;
    #pragma unroll
    for (int n = 0; n < DSTATE; n += 4)
        *(float4*)(hp + n) = make_float4(h[n], h[n + 1], h[n + 2], h[n + 3]);
    sdelta[(size_t)c * DINNER + d] = sd;
}

// ---------------------------------------------------------------------------
// Pass 2: per (d,n) sequential scan over chunk states; in-place -> Hin[c].
// ---------------------------------------------------------------------------
__global__ __launch_bounds__(256) void k_scan2(
    float* __restrict__ hloc, const float* __restrict__ sdelta,
    const void* __restrict__ Alog, size_t aoff,
    const int* __restrict__ flagp)
{
    const bool bf = (*flagp != 0);
    const int gid = blockIdx.x * 256 + threadIdx.x;   // 0 .. DINNER*DSTATE-1
    const int d = gid >> 4, n = gid & 15;
    const float A = -__expf(ldin(Alog, aoff + (size_t)d * DSTATE + n, bf));
    float carry = 0.f;
    for (int c = 0; c < NCHUNK; ++c) {
        const size_t idx = ((size_t)c * DINNER + d) * DSTATE + n;
        const float tmp = hloc[idx];
        hloc[idx] = carry;
        const float P = __expf(A * sdelta[(size_t)c * DINNER + d]);
        carry = fmaf(P, carry, tmp);
    }
}

// ---------------------------------------------------------------------------
// Pass 3: local scan seeded with Hin[c]; epilogue y=(C.h+uc*D)*silu(z),
// written as bf16 (out_proj A-operand).
// ---------------------------------------------------------------------------
__global__ __launch_bounds__(128) void k_scan3(
    const float* __restrict__ delta, const float* __restrict__ uc,
    const float* __restrict__ xz, const float* __restrict__ xdbl,
    const void* __restrict__ Alog, size_t aoff,
    const void* __restrict__ Dp, size_t doff,
    const float* __restrict__ hin, unsigned short* __restrict__ y,
    const int* __restrict__ flagp)
{
    const bool bf = (*flagp != 0);
    __shared__ float sBC[CHUNK][2 * DSTATE];
    const int d = blockIdx.x * 128 + threadIdx.x;
    const int c = blockIdx.y;
    const int t0 = c * CHUNK;
    float Arow[DSTATE];
    #pragma unroll
    for (int n = 0; n < DSTATE; ++n)
        Arow[n] = -__expf(ldin(Alog, aoff + (size_t)d * DSTATE + n, bf));
    const float Dv = ldin(Dp, doff + d, bf);
    #pragma unroll
    for (int r = 0; r < 16; ++r) {
        const int idx = r * 128 + threadIdx.x;
        const int tt = idx >> 5, n = idx & 31;
        sBC[tt][n] = xdbl[(size_t)(t0 + tt) * XDIM + DTRANK + n];
    }
    __syncthreads();
    float h[DSTATE];
    const float* hp = hin + ((size_t)c * DINNER + d) * DSTATE;
    #pragma unroll
    for (int n = 0; n < DSTATE; n += 4) {
        const float4 v = *(const float4*)(hp + n);
        h[n] = v.x; h[n + 1] = v.y; h[n + 2] = v.z; h[n + 3] = v.w;
    }
    for (int ti = 0; ti < CHUNK; ++ti) {
        const int t = t0 + ti;
        const float d_t = delta[(size_t)t * DINNER + d];
        const float u_t = uc[(size_t)t * DINNER + d];
        const float z_t = xz[(size_t)t * (2 * DINNER) + DINNER + d];
        const float du = d_t * u_t;
        float dot = 0.f;
        #pragma unroll
        for (int n = 0; n < DSTATE; ++n) {
            const float dA = __expf(d_t * Arow[n]);
            h[n] = fmaf(dA, h[n], du * sBC[ti][n]);
            dot = fmaf(h[n], sBC[ti][DSTATE + n], dot);
        }
        const float sig = 1.f / (1.f + __expf(-z_t));
        y[(size_t)t * DINNER + d] = f2bf((dot + u_t * Dv) * (z_t * sig));
    }
}

// ---------------------------------------------------------------------------
// Final: out = (hidden + residual), dtype per flag
// ---------------------------------------------------------------------------
__global__ __launch_bounds__(256) void k_final(
    const float* __restrict__ hh, const float* __restrict__ resid,
    void* __restrict__ out, const int* __restrict__ flagp)
{
    const bool bf = (*flagp != 0);
    const int i = (blockIdx.x * 256 + threadIdx.x) * 4;
    const float4 a = *(const float4*)(hh + i);
    const float4 b = *(const float4*)(resid + i);
    const float o0 = a.x + b.x, o1 = a.y + b.y, o2 = a.z + b.z, o3 = a.w + b.w;
    if (bf) {
        ushort4 o;
        o.x = f2bf(o0); o.y = f2bf(o1); o.z = f2bf(o2); o.w = f2bf(o3);
        *(ushort4*)((unsigned short*)out + i) = o;
    } else {
        *(float4*)((float*)out + i) = make_float4(o0, o1, o2, o3);
    }
}

extern "C" void kernel_launch(void* const* d_in, const int* in_sizes, int n_in,
                              void* d_out, int out_size, void* d_ws, size_t ws_size,
                              hipStream_t stream)
{
    const void* hs    = d_in[0];
    const void* normw = d_in[1];
    const void* ipw   = d_in[2];
    const void* cw    = d_in[3];
    const void* cb    = d_in[4];
    const void* xpw   = d_in[5];
    const void* dtw   = d_in[6];
    const void* dtb   = d_in[7];
    const void* Alog  = d_in[8];
    const void* Dp    = d_in[9];
    const void* opw   = d_in[10];

    // fp32 region
    float* ws    = (float*)d_ws;
    float* resid = ws;                                       // 2M
    float* hh    = resid  + (size_t)L_SEQ * DMODEL;          // 2M (scan scratch overlay)
    float* xzb   = hh     + (size_t)L_SEQ * DMODEL;          // 8M
    float* ucb   = xzb    + (size_t)L_SEQ * 2 * DINNER;      // 4M
    float* xdblb = ucb    + (size_t)L_SEQ * DINNER;          // 196608
    float* deltab= xdblb  + (size_t)L_SEQ * XDIM;            // 4M (x_proj parts overlay)
    // bf16 region
    unsigned short* hn_bf   = (unsigned short*)(deltab + (size_t)L_SEQ * DINNER);
    unsigned short* uch     = hn_bf   + (size_t)L_SEQ * DMODEL;   // 4M
    unsigned short* xdbl_bf = uch     + (size_t)L_SEQ * DINNER;   // 196608
    unsigned short* y_bf    = xdbl_bf + (size_t)L_SEQ * XDIM;     // 4M
    int*            flagp   = (int*)(y_bf + (size_t)L_SEQ * DINNER);

    // scan scratch overlays hh (dead between addnorm-read and out_proj-write)
    float* hlocb   = hh;                                     // 1,048,576 floats
    float* sdeltab = hh + (size_t)NCHUNK * DINNER * DSTATE;  // 65,536 floats
    // x_proj partials overlay deltab (dead until dt_proj writes it)
    float* partsb  = deltab;                                 // KSPLIT*L*XDIM = 1.57M floats

    k_detect<<<1, 1, 0, stream>>>((const unsigned int*)Alog, flagp);

    for (int i = 0; i < NLAYER; ++i) {
        const size_t o_ipw = (size_t)i * 2 * DINNER * DMODEL;
        const size_t o_xpw = (size_t)i * XDIM * DINNER;
        const size_t o_dtw = (size_t)i * DINNER * DTRANK;
        const size_t o_opw = (size_t)i * DMODEL * DINNER;
        const size_t o_al  = (size_t)i * DINNER * DSTATE;

        k_addnorm<<<L_SEQ, 256, 0, stream>>>(
            hh, hs, resid, hn_bf, normw, (size_t)i * DMODEL, i == 0 ? 1 : 0, flagp);
        // in_proj: (2048 x 1024) @ (4096 x 1024)^T -> xz fp32
        k_gemm_mfma<<<dim3(16, 32), 256, 0, stream>>>(
            hn_bf, DMODEL, ipw, o_ipw, DMODEL,
            xzb, 2 * DINNER, 0, 2 * DINNER, DMODEL, nullptr, 0, 0, flagp);
        k_conv<<<(L_SEQ * DINNER) / 256, 256, 0, stream>>>(
            xzb, cw, (size_t)i * DINNER * DCONV, cb, (size_t)i * DINNER, ucb, uch, flagp);
        // x_proj split-K: (2048 x 2048) @ (96 x 2048)^T, 8 slices -> parts
        k_gemm_mfma<<<dim3(16, 1, KSPLIT), 256, 0, stream>>>(
            uch, DINNER, xpw, o_xpw, DINNER,
            partsb, XDIM, (size_t)L_SEQ * XDIM, XDIM, DINNER / KSPLIT,
            nullptr, 0, 0, flagp);
        k_reduce<<<(L_SEQ * XDIM) / 256, 256, 0, stream>>>(partsb, xdblb, xdbl_bf);
        // dt_proj + softplus: (2048 x 64) @ (2048 x 64)^T -> delta fp32
        k_gemm_mfma<<<dim3(16, 16), 256, 0, stream>>>(
            xdbl_bf, XDIM, dtw, o_dtw, DTRANK,
            deltab, DINNER, 0, DINNER, DTRANK, dtb, (size_t)i * DINNER, 1, flagp);
        // chunk-parallel selective scan
        k_scan1<<<dim3(DINNER / 128, NCHUNK), 128, 0, stream>>>(
            deltab, ucb, xdblb, Alog, o_al, hlocb, sdeltab, flagp);
        k_scan2<<<(DINNER * DSTATE) / 256, 256, 0, stream>>>(
            hlocb, sdeltab, Alog, o_al, flagp);
        k_scan3<<<dim3(DINNER / 128, NCHUNK), 128, 0, stream>>>(
            deltab, ucb, xzb, xdblb, Alog, o_al, Dp, (size_t)i * DINNER,
            hlocb, y_bf, flagp);
        // out_proj: (2048 x 2048) @ (1024 x 2048)^T -> hh fp32
        k_gemm_mfma<<<dim3(16, 8), 256, 0, stream>>>(
            y_bf, DINNER, opw, o_opw, DINNER,
            hh, DMODEL, 0, DMODEL, DINNER, nullptr, 0, 0, flagp);
    }
    k_final<<<(L_SEQ * DMODEL) / 1024, 256, 0, stream>>>(hh, resid, d_out, flagp);
}

// Round 5
// 1183.137 us; speedup vs baseline: 6.4111x; 1.1623x over previous
//
#include <hip/hip_runtime.h>
#include <hip/hip_bf16.h>

// Problem constants (from reference)
#define L_SEQ   2048
#define DMODEL  1024
#define DINNER  2048
#define DSTATE  16
#define DTRANK  64
#define DCONV   4
#define NLAYER  4
#define XDIM    96   // DTRANK + 2*DSTATE
#define CHUNK   64
#define NCHUNK  (L_SEQ / CHUNK)   // 32
#define KSPLIT  16                // x_proj split-K factor

typedef __attribute__((ext_vector_type(8))) short bf16x8;
typedef __attribute__((ext_vector_type(4))) float f32x4;

__device__ __forceinline__ float bf2f(unsigned short u) {
    union { unsigned int i; float f; } v; v.i = ((unsigned int)u) << 16; return v.f;
}
__device__ __forceinline__ unsigned short f2bf(float f) {
    union { float f; unsigned int i; } v; v.f = f;
    unsigned int x = v.i;
    unsigned int r = (x + 0x7fffu + ((x >> 16) & 1u)) >> 16;  // RTNE
    return (unsigned short)r;
}
// pack two fp32 -> two bf16 in a u32 (round-to-nearest half-up; staging only)
__device__ __forceinline__ unsigned int pk2(float a, float b) {
    union { float f; unsigned int i; } ua, ub; ua.f = a; ub.f = b;
    const unsigned int x = (ua.i + 0x8000u) >> 16;
    const unsigned int y = (ub.i + 0x8000u) >> 16;
    return x | (y << 16);
}
__device__ __forceinline__ float ldin(const void* p, size_t idx, bool bf) {
    return bf ? bf2f(((const unsigned short*)p)[idx]) : ((const float*)p)[idx];
}

// ---------------------------------------------------------------------------
// Dtype detector: A_log[0] = log(1) = 0.  fp32 -> first u32 == 0x00000000.
// ---------------------------------------------------------------------------
__global__ void k_detect(const unsigned int* __restrict__ Alog_u32, int* __restrict__ flag) {
    *flag = (Alog_u32[0] != 0u) ? 1 : 0;
}

// ---------------------------------------------------------------------------
// Fused residual add + RMSNorm -> bf16 normed output.
// ---------------------------------------------------------------------------
__global__ __launch_bounds__(256) void k_addnorm(
    const float* __restrict__ hid, const void* __restrict__ hs,
    float* __restrict__ resid, unsigned short* __restrict__ hnorm,
    const void* __restrict__ w, size_t woff, int first,
    const int* __restrict__ flagp)
{
    const bool bf = (*flagp != 0);
    const int row = blockIdx.x;
    const int col = threadIdx.x * 4;
    const size_t base = (size_t)row * DMODEL + col;
    float r[4];
    if (first) {
        if (bf) {
            const ushort4 v = *(const ushort4*)((const unsigned short*)hs + base);
            r[0] = bf2f(v.x); r[1] = bf2f(v.y); r[2] = bf2f(v.z); r[3] = bf2f(v.w);
        } else {
            const float4 v = *(const float4*)((const float*)hs + base);
            r[0] = v.x; r[1] = v.y; r[2] = v.z; r[3] = v.w;
        }
    } else {
        const float4 hv = *(const float4*)(hid + base);
        const float4 rv = *(const float4*)(resid + base);
        r[0] = hv.x + rv.x; r[1] = hv.y + rv.y; r[2] = hv.z + rv.z; r[3] = hv.w + rv.w;
    }
    *(float4*)(resid + base) = make_float4(r[0], r[1], r[2], r[3]);
    float ss = r[0]*r[0] + r[1]*r[1] + r[2]*r[2] + r[3]*r[3];
    #pragma unroll
    for (int o = 32; o > 0; o >>= 1) ss += __shfl_down(ss, o);
    __shared__ float red[4];
    const int lane = threadIdx.x & 63, wv = threadIdx.x >> 6;
    if (lane == 0) red[wv] = ss;
    __syncthreads();
    const float total = red[0] + red[1] + red[2] + red[3];
    const float scale = rsqrtf(total * (1.0f / DMODEL) + 1e-5f);
    const float w0 = ldin(w, woff + col + 0, bf), w1 = ldin(w, woff + col + 1, bf);
    const float w2 = ldin(w, woff + col + 2, bf), w3 = ldin(w, woff + col + 3, bf);
    ushort4 o;
    o.x = f2bf(r[0] * scale * w0); o.y = f2bf(r[1] * scale * w1);
    o.z = f2bf(r[2] * scale * w2); o.w = f2bf(r[3] * scale * w3);
    *(ushort4*)(hnorm + base) = o;
}

// ---------------------------------------------------------------------------
// MFMA NT GEMM: C[M,N] = A[M,K]_bf16 * W[N,K]^T (input dtype).
// 128x128 tile, 256 thr (2x2 waves of 64x64), BK=32, mfma_f32_16x16x32_bf16.
// LDS: row stride 32 bf16 (64 B), chunk(16B)-swizzle pos = chunk ^ (row&3);
// threads stage chunks {b, b+2} (b = tid&1) -> conflict-free b128 write+read.
// Register prefetch: next K-tile loads issue right after first barrier and
// complete during current tile's MFMA.
// blockIdx.z = split-K slice (k0 = z*Kslice, C += z*czstride).
// mode 1: C = softplus(acc + bias[n]).
// ---------------------------------------------------------------------------
__global__ __launch_bounds__(256) void k_gemm_mfma(
    const unsigned short* __restrict__ A, int lda,
    const void* __restrict__ W, size_t woff, int ldw,
    float* __restrict__ C, int ldc, size_t czstride,
    int N, int Kslice,
    const void* __restrict__ bias, size_t boff, int mode,
    const int* __restrict__ flagp)
{
    const bool bf = (*flagp != 0);
    __shared__ unsigned short lA[128 * 32];
    __shared__ unsigned short lB[128 * 32];
    const int tid = threadIdx.x;
    const int m0 = blockIdx.x * 128;
    const int n0 = blockIdx.y * 128;
    const int k0 = blockIdx.z * Kslice;
    float* Cz = C + (size_t)blockIdx.z * czstride;

    const int w    = tid >> 6;
    const int lane = tid & 63;
    const int wm = (w >> 1) * 64, wn = (w & 1) * 64;
    const int m16 = lane & 15, kg = lane >> 4;
    const int swz = (kg ^ (m16 & 3)) * 8;      // read-side swizzled k-offset

    const int sr  = tid >> 1;                  // staging row 0..127
    const int cb0 = tid & 1;                   // stage chunks cb0, cb0+2
    const int e0  = cb0 * 8, e1 = e0 + 16;     // global element offsets
    const int p0  = (cb0 ^ (sr & 3)) * 8;      // swizzled LDS positions
    const int p1  = ((cb0 + 2) ^ (sr & 3)) * 8;
    const int sA  = sr * 32;

    const unsigned short* Arow = A + (size_t)(m0 + sr) * lda;
    const int nrow = n0 + sr;
    const bool nok = (nrow < N);
    const unsigned short* Wrow_bf = (const unsigned short*)W + woff + (size_t)nrow * ldw;
    const float*          Wrow_f  = (const float*)W + woff + (size_t)nrow * ldw;

    f32x4 acc[4][4];
    #pragma unroll
    for (int i = 0; i < 4; ++i)
        #pragma unroll
        for (int j = 0; j < 4; ++j)
            acc[i][j] = (f32x4){0.f, 0.f, 0.f, 0.f};

    uint4 ra0, ra1, rb0, rb1;
    // prologue: load tile 0
    {
        ra0 = *(const uint4*)(Arow + k0 + e0);
        ra1 = *(const uint4*)(Arow + k0 + e1);
        rb0 = (uint4){0u,0u,0u,0u}; rb1 = rb0;
        if (nok) {
            if (bf) {
                rb0 = *(const uint4*)(Wrow_bf + k0 + e0);
                rb1 = *(const uint4*)(Wrow_bf + k0 + e1);
            } else {
                const float4 f0 = *(const float4*)(Wrow_f + k0 + e0);
                const float4 f1 = *(const float4*)(Wrow_f + k0 + e0 + 4);
                const float4 f2 = *(const float4*)(Wrow_f + k0 + e1);
                const float4 f3 = *(const float4*)(Wrow_f + k0 + e1 + 4);
                rb0.x = pk2(f0.x, f0.y); rb0.y = pk2(f0.z, f0.w);
                rb0.z = pk2(f1.x, f1.y); rb0.w = pk2(f1.z, f1.w);
                rb1.x = pk2(f2.x, f2.y); rb1.y = pk2(f2.z, f2.w);
                rb1.z = pk2(f3.x, f3.y); rb1.w = pk2(f3.z, f3.w);
            }
        }
    }

    for (int kb = 0; kb < Kslice; kb += 32) {
        *(uint4*)&lA[sA + p0] = ra0;
        *(uint4*)&lA[sA + p1] = ra1;
        *(uint4*)&lB[sA + p0] = rb0;
        *(uint4*)&lB[sA + p1] = rb1;
        __syncthreads();
        if (kb + 32 < Kslice) {   // prefetch next tile (completes during MFMA)
            const int kk = k0 + kb + 32;
            ra0 = *(const uint4*)(Arow + kk + e0);
            ra1 = *(const uint4*)(Arow + kk + e1);
            if (nok) {
                if (bf) {
                    rb0 = *(const uint4*)(Wrow_bf + kk + e0);
                    rb1 = *(const uint4*)(Wrow_bf + kk + e1);
                } else {
                    const float4 f0 = *(const float4*)(Wrow_f + kk + e0);
                    const float4 f1 = *(const float4*)(Wrow_f + kk + e0 + 4);
                    const float4 f2 = *(const float4*)(Wrow_f + kk + e1);
                    const float4 f3 = *(const float4*)(Wrow_f + kk + e1 + 4);
                    rb0.x = pk2(f0.x, f0.y); rb0.y = pk2(f0.z, f0.w);
                    rb0.z = pk2(f1.x, f1.y); rb0.w = pk2(f1.z, f1.w);
                    rb1.x = pk2(f2.x, f2.y); rb1.y = pk2(f2.z, f2.w);
                    rb1.z = pk2(f3.x, f3.y); rb1.w = pk2(f3.z, f3.w);
                }
            }
        }
        bf16x8 af[4], bfr[4];
        #pragma unroll
        for (int i = 0; i < 4; ++i)
            af[i] = *(const bf16x8*)&lA[(wm + i * 16 + m16) * 32 + swz];
        #pragma unroll
        for (int j = 0; j < 4; ++j)
            bfr[j] = *(const bf16x8*)&lB[(wn + j * 16 + m16) * 32 + swz];
        #pragma unroll
        for (int i = 0; i < 4; ++i)
            #pragma unroll
            for (int j = 0; j < 4; ++j)
                acc[i][j] = __builtin_amdgcn_mfma_f32_16x16x32_bf16(af[i], bfr[j], acc[i][j], 0, 0, 0);
        __syncthreads();
    }
    // epilogue: D row=(lane>>4)*4+reg, col=lane&15  [verified gfx950 layout]
    const int rowb = (lane >> 4) * 4;
    #pragma unroll
    for (int j = 0; j < 4; ++j) {
        const int col = n0 + wn + j * 16 + m16;
        if (col < N) {
            float bv = 0.f;
            if (mode == 1) bv = ldin(bias, boff + col, bf);
            #pragma unroll
            for (int i = 0; i < 4; ++i) {
                #pragma unroll
                for (int r = 0; r < 4; ++r) {
                    const int row = m0 + wm + i * 16 + rowb + r;
                    float v = acc[i][j][r];
                    if (mode == 1) { v += bv; v = (v > 20.f) ? v : log1pf(__expf(v)); }
                    Cz[(size_t)row * ldc + col] = v;
                }
            }
        }
    }
}

// ---------------------------------------------------------------------------
// Causal depthwise conv (k=4) + bias + SiLU. Dual write fp32 + bf16.
// ---------------------------------------------------------------------------
__global__ __launch_bounds__(256) void k_conv(
    const float* __restrict__ xz, const void* __restrict__ cw, size_t cwoff,
    const void* __restrict__ cb, size_t cboff,
    float* __restrict__ uc, unsigned short* __restrict__ uch,
    const int* __restrict__ flagp)
{
    const bool bf = (*flagp != 0);
    const int idx = blockIdx.x * 256 + threadIdx.x;
    const int d = idx & (DINNER - 1);
    const int l = idx >> 11;
    const float w0 = ldin(cw, cwoff + d * 4 + 0, bf), w1 = ldin(cw, cwoff + d * 4 + 1, bf);
    const float w2 = ldin(cw, cwoff + d * 4 + 2, bf), w3 = ldin(cw, cwoff + d * 4 + 3, bf);
    float acc = ldin(cb, cboff + d, bf);
    if (l >= 3) acc = fmaf(xz[(size_t)(l - 3) * (2 * DINNER) + d], w0, acc);
    if (l >= 2) acc = fmaf(xz[(size_t)(l - 2) * (2 * DINNER) + d], w1, acc);
    if (l >= 1) acc = fmaf(xz[(size_t)(l - 1) * (2 * DINNER) + d], w2, acc);
    acc = fmaf(xz[(size_t)l * (2 * DINNER) + d], w3, acc);
    const float sig = 1.f / (1.f + __expf(-acc));
    const float v = acc * sig;
    uc[(size_t)l * DINNER + d] = v;
    uch[(size_t)l * DINNER + d] = f2bf(v);
}

// ---------------------------------------------------------------------------
// x_proj split-K reduce: xdbl = sum of KSPLIT partials; dual write fp32+bf16.
// ---------------------------------------------------------------------------
__global__ __launch_bounds__(256) void k_reduce(
    const float* __restrict__ parts, float* __restrict__ xdbl,
    unsigned short* __restrict__ xdbl_bf)
{
    const int idx = blockIdx.x * 256 + threadIdx.x;   // 0 .. L*XDIM-1
    float s = 0.f;
    #pragma unroll
    for (int z = 0; z < KSPLIT; ++z)
        s += parts[(size_t)z * L_SEQ * XDIM + idx];
    xdbl[idx] = s;
    xdbl_bf[idx] = f2bf(s);
}

// ---------------------------------------------------------------------------
// out_proj split-K=2 partial add -> hh fp32.
// ---------------------------------------------------------------------------
__global__ __launch_bounds__(256) void k_addparts(
    const float* __restrict__ parts, float* __restrict__ o)
{
    const int i = (blockIdx.x * 256 + threadIdx.x) * 4;
    const float4 a = *(const float4*)(parts + i);
    const float4 b = *(const float4*)(parts + (size_t)L_SEQ * DMODEL + i);
    *(float4*)(o + i) = make_float4(a.x + b.x, a.y + b.y, a.z + b.z, a.w + b.w);
}

// ---------------------------------------------------------------------------
// Chunked selective scan, pass 1: local scan from h=0 per (channels, chunk).
// ---------------------------------------------------------------------------
__global__ __launch_bounds__(128) void k_scan1(
    const float* __restrict__ delta, const float* __restrict__ uc,
    const float* __restrict__ xdbl,
    const void* __restrict__ Alog, size_t aoff,
    float* __restrict__ hloc, float* __restrict__ sdelta,
    const int* __restrict__ flagp)
{
    const bool bf = (*flagp != 0);
    __shared__ float sB[CHUNK][DSTATE];
    const int d = blockIdx.x * 128 + threadIdx.x;
    const int c = blockIdx.y;
    const int t0 = c * CHUNK;
    float Arow[DSTATE];
    #pragma unroll
    for (int n = 0; n < DSTATE; ++n)
        Arow[n] = -__expf(ldin(Alog, aoff + (size_t)d * DSTATE + n, bf));
    #pragma unroll
    for (int r = 0; r < 8; ++r) {
        const int idx = r * 128 + threadIdx.x;
        const int tt = idx >> 4, n = idx & 15;
        sB[tt][n] = xdbl[(size_t)(t0 + tt) * XDIM + DTRANK + n];
    }
    __syncthreads();
    float h[DSTATE];
    #pragma unroll
    for (int n = 0; n < DSTATE; ++n) h[n] = 0.f;
    float sd = 0.f;
    for (int ti = 0; ti < CHUNK; ++ti) {
        const int t = t0 + ti;
        const float d_t = delta[(size_t)t * DINNER + d];
        const float u_t = uc[(size_t)t * DINNER + d];
        sd += d_t;
        const float du = d_t * u_t;
        #pragma unroll
        for (int n = 0; n < DSTATE; ++n) {
            const float dA = __expf(d_t * Arow[n]);
            h[n] = fmaf(dA, h[n], du * sB[ti][n]);
        }
    }
    float* hp = hloc + ((size_t)c * DINNER + d) * DSTATE;
    #pragma unroll
    for (int n = 0; n < DSTATE; n += 4)
        *(float4*)(hp + n) = make_float4(h[n], h[n + 1], h[n + 2], h[n + 3]);
    sdelta[(size_t)c * DINNER + d] = sd;
}

// ---------------------------------------------------------------------------
// Pass 2: per (d,n) sequential scan over chunk states; in-place -> Hin[c].
// ---------------------------------------------------------------------------
__global__ __launch_bounds__(256) void k_scan2(
    float* __restrict__ hloc, const float* __restrict__ sdelta,
    const void* __restrict__ Alog, size_t aoff,
    const int* __restrict__ flagp)
{
    const bool bf = (*flagp != 0);
    const int gid = blockIdx.x * 256 + threadIdx.x;
    const int d = gid >> 4, n = gid & 15;
    const float A = -__expf(ldin(Alog, aoff + (size_t)d * DSTATE + n, bf));
    float carry = 0.f;
    for (int c = 0; c < NCHUNK; ++c) {
        const size_t idx = ((size_t)c * DINNER + d) * DSTATE + n;
        const float tmp = hloc[idx];
        hloc[idx] = carry;
        const float P = __expf(A * sdelta[(size_t)c * DINNER + d]);
        carry = fmaf(P, carry, tmp);
    }
}

// ---------------------------------------------------------------------------
// Pass 3: local scan seeded with Hin[c]; y=(C.h+uc*D)*silu(z) as bf16.
// ---------------------------------------------------------------------------
__global__ __launch_bounds__(128) void k_scan3(
    const float* __restrict__ delta, const float* __restrict__ uc,
    const float* __restrict__ xz, const float* __restrict__ xdbl,
    const void* __restrict__ Alog, size_t aoff,
    const void* __restrict__ Dp, size_t doff,
    const float* __restrict__ hin, unsigned short* __restrict__ y,
    const int* __restrict__ flagp)
{
    const bool bf = (*flagp != 0);
    __shared__ float sBC[CHUNK][2 * DSTATE];
    const int d = blockIdx.x * 128 + threadIdx.x;
    const int c = blockIdx.y;
    const int t0 = c * CHUNK;
    float Arow[DSTATE];
    #pragma unroll
    for (int n = 0; n < DSTATE; ++n)
        Arow[n] = -__expf(ldin(Alog, aoff + (size_t)d * DSTATE + n, bf));
    const float Dv = ldin(Dp, doff + d, bf);
    #pragma unroll
    for (int r = 0; r < 16; ++r) {
        const int idx = r * 128 + threadIdx.x;
        const int tt = idx >> 5, n = idx & 31;
        sBC[tt][n] = xdbl[(size_t)(t0 + tt) * XDIM + DTRANK + n];
    }
    __syncthreads();
    float h[DSTATE];
    const float* hp = hin + ((size_t)c * DINNER + d) * DSTATE;
    #pragma unroll
    for (int n = 0; n < DSTATE; n += 4) {
        const float4 v = *(const float4*)(hp + n);
        h[n] = v.x; h[n + 1] = v.y; h[n + 2] = v.z; h[n + 3] = v.w;
    }
    for (int ti = 0; ti < CHUNK; ++ti) {
        const int t = t0 + ti;
        const float d_t = delta[(size_t)t * DINNER + d];
        const float u_t = uc[(size_t)t * DINNER + d];
        const float z_t = xz[(size_t)t * (2 * DINNER) + DINNER + d];
        const float du = d_t * u_t;
        float dot = 0.f;
        #pragma unroll
        for (int n = 0; n < DSTATE; ++n) {
            const float dA = __expf(d_t * Arow[n]);
            h[n] = fmaf(dA, h[n], du * sBC[ti][n]);
            dot = fmaf(h[n], sBC[ti][DSTATE + n], dot);
        }
        const float sig = 1.f / (1.f + __expf(-z_t));
        y[(size_t)t * DINNER + d] = f2bf((dot + u_t * Dv) * (z_t * sig));
    }
}

// ---------------------------------------------------------------------------
// Final: out = (hidden + residual), dtype per flag
// ---------------------------------------------------------------------------
__global__ __launch_bounds__(256) void k_final(
    const float* __restrict__ hh, const float* __restrict__ resid,
    void* __restrict__ out, const int* __restrict__ flagp)
{
    const bool bf = (*flagp != 0);
    const int i = (blockIdx.x * 256 + threadIdx.x) * 4;
    const float4 a = *(const float4*)(hh + i);
    const float4 b = *(const float4*)(resid + i);
    const float o0 = a.x + b.x, o1 = a.y + b.y, o2 = a.z + b.z, o3 = a.w + b.w;
    if (bf) {
        ushort4 o;
        o.x = f2bf(o0); o.y = f2bf(o1); o.z = f2bf(o2); o.w = f2bf(o3);
        *(ushort4*)((unsigned short*)out + i) = o;
    } else {
        *(float4*)((float*)out + i) = make_float4(o0, o1, o2, o3);
    }
}

extern "C" void kernel_launch(void* const* d_in, const int* in_sizes, int n_in,
                              void* d_out, int out_size, void* d_ws, size_t ws_size,
                              hipStream_t stream)
{
    const void* hs    = d_in[0];
    const void* normw = d_in[1];
    const void* ipw   = d_in[2];
    const void* cw    = d_in[3];
    const void* cb    = d_in[4];
    const void* xpw   = d_in[5];
    const void* dtw   = d_in[6];
    const void* dtb   = d_in[7];
    const void* Alog  = d_in[8];
    const void* Dp    = d_in[9];
    const void* opw   = d_in[10];

    // fp32 region
    float* ws    = (float*)d_ws;
    float* resid = ws;                                       // 2M
    float* hh    = resid  + (size_t)L_SEQ * DMODEL;          // 2M (scan scratch overlay)
    float* xzb   = hh     + (size_t)L_SEQ * DMODEL;          // 8M
    float* ucb   = xzb    + (size_t)L_SEQ * 2 * DINNER;      // 4M
    float* xdblb = ucb    + (size_t)L_SEQ * DINNER;          // 196608
    float* deltab= xdblb  + (size_t)L_SEQ * XDIM;            // 4M (parts overlays)
    // bf16 region
    unsigned short* hn_bf   = (unsigned short*)(deltab + (size_t)L_SEQ * DINNER);
    unsigned short* uch     = hn_bf   + (size_t)L_SEQ * DMODEL;
    unsigned short* xdbl_bf = uch     + (size_t)L_SEQ * DINNER;
    unsigned short* y_bf    = xdbl_bf + (size_t)L_SEQ * XDIM;
    int*            flagp   = (int*)(y_bf + (size_t)L_SEQ * DINNER);

    // scan scratch overlays hh (dead between addnorm-read and out_proj-write)
    float* hlocb   = hh;                                     // 1,048,576 floats
    float* sdeltab = hh + (size_t)NCHUNK * DINNER * DSTATE;  // 65,536 floats
    // x_proj partials overlay deltab (dead until dt_proj writes it):
    //   KSPLIT * L * XDIM = 3,145,728 floats <= 4,194,304
    float* partsX  = deltab;
    // out_proj partials overlay deltab (dead after scan3):
    //   2 * L * DMODEL = 4,194,304 floats == capacity
    float* partsO  = deltab;

    k_detect<<<1, 1, 0, stream>>>((const unsigned int*)Alog, flagp);

    for (int i = 0; i < NLAYER; ++i) {
        const size_t o_ipw = (size_t)i * 2 * DINNER * DMODEL;
        const size_t o_xpw = (size_t)i * XDIM * DINNER;
        const size_t o_dtw = (size_t)i * DINNER * DTRANK;
        const size_t o_opw = (size_t)i * DMODEL * DINNER;
        const size_t o_al  = (size_t)i * DINNER * DSTATE;

        k_addnorm<<<L_SEQ, 256, 0, stream>>>(
            hh, hs, resid, hn_bf, normw, (size_t)i * DMODEL, i == 0 ? 1 : 0, flagp);
        // in_proj: (2048 x 1024) @ (4096 x 1024)^T -> xz fp32   [512 blocks]
        k_gemm_mfma<<<dim3(16, 32, 1), 256, 0, stream>>>(
            hn_bf, DMODEL, ipw, o_ipw, DMODEL,
            xzb, 2 * DINNER, 0, 2 * DINNER, DMODEL, nullptr, 0, 0, flagp);
        k_conv<<<(L_SEQ * DINNER) / 256, 256, 0, stream>>>(
            xzb, cw, (size_t)i * DINNER * DCONV, cb, (size_t)i * DINNER, ucb, uch, flagp);
        // x_proj split-K=16: (2048 x 2048) @ (96 x 2048)^T      [256 blocks]
        k_gemm_mfma<<<dim3(16, 1, KSPLIT), 256, 0, stream>>>(
            uch, DINNER, xpw, o_xpw, DINNER,
            partsX, XDIM, (size_t)L_SEQ * XDIM, XDIM, DINNER / KSPLIT,
            nullptr, 0, 0, flagp);
        k_reduce<<<(L_SEQ * XDIM) / 256, 256, 0, stream>>>(partsX, xdblb, xdbl_bf);
        // dt_proj + softplus: (2048 x 64) @ (2048 x 64)^T       [256 blocks]
        k_gemm_mfma<<<dim3(16, 16, 1), 256, 0, stream>>>(
            xdbl_bf, XDIM, dtw, o_dtw, DTRANK,
            deltab, DINNER, 0, DINNER, DTRANK, dtb, (size_t)i * DINNER, 1, flagp);
        // chunk-parallel selective scan
        k_scan1<<<dim3(DINNER / 128, NCHUNK), 128, 0, stream>>>(
            deltab, ucb, xdblb, Alog, o_al, hlocb, sdeltab, flagp);
        k_scan2<<<(DINNER * DSTATE) / 256, 256, 0, stream>>>(
            hlocb, sdeltab, Alog, o_al, flagp);
        k_scan3<<<dim3(DINNER / 128, NCHUNK), 128, 0, stream>>>(
            deltab, ucb, xzb, xdblb, Alog, o_al, Dp, (size_t)i * DINNER,
            hlocb, y_bf, flagp);
        // out_proj split-K=2: (2048 x 2048) @ (1024 x 2048)^T   [256 blocks]
        k_gemm_mfma<<<dim3(16, 8, 2), 256, 0, stream>>>(
            y_bf, DINNER, opw, o_opw, DINNER,
            partsO, DMODEL, (size_t)L_SEQ * DMODEL, DMODEL, DINNER / 2,
            nullptr, 0, 0, flagp);
        k_addparts<<<(L_SEQ * DMODEL) / 1024, 256, 0, stream>>>(partsO, hh);
    }
    k_final<<<(L_SEQ * DMODEL) / 1024, 256, 0, stream>>>(hh, resid, d_out, flagp);
}

// Round 6
// 1122.238 us; speedup vs baseline: 6.7590x; 1.0543x over previous
//
#include <hip/hip_runtime.h>
#include <hip/hip_bf16.h>

// Problem constants (from reference)
#define L_SEQ   2048
#define DMODEL  1024
#define DINNER  2048
#define DSTATE  16
#define DTRANK  64
#define DCONV   4
#define NLAYER  4
#define XDIM    96   // DTRANK + 2*DSTATE
#define CHUNK   64
#define NCHUNK  (L_SEQ / CHUNK)   // 32
#define KSPLIT  16                // x_proj split-K factor

typedef __attribute__((ext_vector_type(8))) short bf16x8;
typedef __attribute__((ext_vector_type(4))) float f32x4;

__device__ __forceinline__ float bf2f(unsigned short u) {
    union { unsigned int i; float f; } v; v.i = ((unsigned int)u) << 16; return v.f;
}
__device__ __forceinline__ unsigned short f2bf(float f) {
    union { float f; unsigned int i; } v; v.f = f;
    unsigned int x = v.i;
    unsigned int r = (x + 0x7fffu + ((x >> 16) & 1u)) >> 16;  // RTNE
    return (unsigned short)r;
}
__device__ __forceinline__ float ldin(const void* p, size_t idx, bool bf) {
    return bf ? bf2f(((const unsigned short*)p)[idx]) : ((const float*)p)[idx];
}

// ---------------------------------------------------------------------------
// Dtype detector: A_log[0] = log(1) = 0.  fp32 -> first u32 == 0x00000000.
// ---------------------------------------------------------------------------
__global__ void k_detect(const unsigned int* __restrict__ Alog_u32, int* __restrict__ flag) {
    *flag = (Alog_u32[0] != 0u) ? 1 : 0;
}

// ---------------------------------------------------------------------------
// Weight cast fp32 -> bf16 (no-op when inputs already bf16; GEMM then reads
// the original pointer). count multiple of 4.
// ---------------------------------------------------------------------------
__global__ __launch_bounds__(256) void k_castw(
    const void* __restrict__ src, size_t eoff, unsigned short* __restrict__ dst,
    int count, const int* __restrict__ flagp)
{
    if (*flagp) return;
    const int i = (blockIdx.x * 256 + threadIdx.x) * 4;
    if (i >= count) return;
    const float4 v = *(const float4*)((const float*)src + eoff + i);
    ushort4 o;
    o.x = f2bf(v.x); o.y = f2bf(v.y); o.z = f2bf(v.z); o.w = f2bf(v.w);
    *(ushort4*)(dst + i) = o;
}

// ---------------------------------------------------------------------------
// Fused residual add + RMSNorm -> bf16 normed output.
// ---------------------------------------------------------------------------
__global__ __launch_bounds__(256) void k_addnorm(
    const float* __restrict__ hid, const void* __restrict__ hs,
    float* __restrict__ resid, unsigned short* __restrict__ hnorm,
    const void* __restrict__ w, size_t woff, int first,
    const int* __restrict__ flagp)
{
    const bool bf = (*flagp != 0);
    const int row = blockIdx.x;
    const int col = threadIdx.x * 4;
    const size_t base = (size_t)row * DMODEL + col;
    float r[4];
    if (first) {
        if (bf) {
            const ushort4 v = *(const ushort4*)((const unsigned short*)hs + base);
            r[0] = bf2f(v.x); r[1] = bf2f(v.y); r[2] = bf2f(v.z); r[3] = bf2f(v.w);
        } else {
            const float4 v = *(const float4*)((const float*)hs + base);
            r[0] = v.x; r[1] = v.y; r[2] = v.z; r[3] = v.w;
        }
    } else {
        const float4 hv = *(const float4*)(hid + base);
        const float4 rv = *(const float4*)(resid + base);
        r[0] = hv.x + rv.x; r[1] = hv.y + rv.y; r[2] = hv.z + rv.z; r[3] = hv.w + rv.w;
    }
    *(float4*)(resid + base) = make_float4(r[0], r[1], r[2], r[3]);
    float ss = r[0]*r[0] + r[1]*r[1] + r[2]*r[2] + r[3]*r[3];
    #pragma unroll
    for (int o = 32; o > 0; o >>= 1) ss += __shfl_down(ss, o);
    __shared__ float red[4];
    const int lane = threadIdx.x & 63, wv = threadIdx.x >> 6;
    if (lane == 0) red[wv] = ss;
    __syncthreads();
    const float total = red[0] + red[1] + red[2] + red[3];
    const float scale = rsqrtf(total * (1.0f / DMODEL) + 1e-5f);
    const float w0 = ldin(w, woff + col + 0, bf), w1 = ldin(w, woff + col + 1, bf);
    const float w2 = ldin(w, woff + col + 2, bf), w3 = ldin(w, woff + col + 3, bf);
    ushort4 o;
    o.x = f2bf(r[0] * scale * w0); o.y = f2bf(r[1] * scale * w1);
    o.z = f2bf(r[2] * scale * w2); o.w = f2bf(r[3] * scale * w3);
    *(ushort4*)(hnorm + base) = o;
}

// ---------------------------------------------------------------------------
// MFMA NT GEMM: C[M,N] = A[M,K]_bf16 * W[N,K]^T_bf16.
// Grid TRANSPOSED for L2 locality: blockIdx.x = n-tile (partitions W across
// XCDs under round-robin dispatch), blockIdx.y = m-tile.
// W pointer: orig input if bf16, else pre-cast buffer (flag-selected).
// 128x128 tile, 256 thr, BK=32, swizzled LDS (stride 32 bf16, chunk^row&3),
// register prefetch of next K-tile.
// blockIdx.z = split-K slice.  mode: 0 = fp32 C, 1 = softplus+bias fp32 C,
// 2 = bf16 C.
// ---------------------------------------------------------------------------
__global__ __launch_bounds__(256) void k_gemm_mfma(
    const unsigned short* __restrict__ A, int lda,
    const void* __restrict__ Worig, size_t woff,
    const unsigned short* __restrict__ Wconv, int ldw,
    void* __restrict__ C, int ldc, size_t czstride,
    int N, int Kslice,
    const void* __restrict__ bias, size_t boff, int mode,
    const int* __restrict__ flagp)
{
    const bool bf = (*flagp != 0);
    __shared__ unsigned short lA[128 * 32];
    __shared__ unsigned short lB[128 * 32];
    const int tid = threadIdx.x;
    const int n0 = blockIdx.x * 128;
    const int m0 = blockIdx.y * 128;
    const int k0 = blockIdx.z * Kslice;

    const int w    = tid >> 6;
    const int lane = tid & 63;
    const int wm = (w >> 1) * 64, wn = (w & 1) * 64;
    const int m16 = lane & 15, kg = lane >> 4;
    const int swz = (kg ^ (m16 & 3)) * 8;      // read-side swizzled k-offset

    const int sr  = tid >> 1;                  // staging row 0..127
    const int cb0 = tid & 1;                   // stage chunks cb0, cb0+2
    const int e0  = cb0 * 8, e1 = e0 + 16;     // global element offsets
    const int p0  = (cb0 ^ (sr & 3)) * 8;      // swizzled LDS positions
    const int p1  = ((cb0 + 2) ^ (sr & 3)) * 8;
    const int sA  = sr * 32;

    const unsigned short* Arow = A + (size_t)(m0 + sr) * lda;
    const int nrow = n0 + sr;
    const bool nok = (nrow < N);
    const unsigned short* Wbase = bf ? ((const unsigned short*)Worig + woff) : Wconv;
    const unsigned short* Wrow  = Wbase + (size_t)nrow * ldw;

    f32x4 acc[4][4];
    #pragma unroll
    for (int i = 0; i < 4; ++i)
        #pragma unroll
        for (int j = 0; j < 4; ++j)
            acc[i][j] = (f32x4){0.f, 0.f, 0.f, 0.f};

    uint4 ra0, ra1, rb0, rb1;
    ra0 = *(const uint4*)(Arow + k0 + e0);
    ra1 = *(const uint4*)(Arow + k0 + e1);
    rb0 = (uint4){0u,0u,0u,0u}; rb1 = rb0;
    if (nok) {
        rb0 = *(const uint4*)(Wrow + k0 + e0);
        rb1 = *(const uint4*)(Wrow + k0 + e1);
    }

    for (int kb = 0; kb < Kslice; kb += 32) {
        *(uint4*)&lA[sA + p0] = ra0;
        *(uint4*)&lA[sA + p1] = ra1;
        *(uint4*)&lB[sA + p0] = rb0;
        *(uint4*)&lB[sA + p1] = rb1;
        __syncthreads();
        if (kb + 32 < Kslice) {   // prefetch next tile (completes during MFMA)
            const int kk = k0 + kb + 32;
            ra0 = *(const uint4*)(Arow + kk + e0);
            ra1 = *(const uint4*)(Arow + kk + e1);
            if (nok) {
                rb0 = *(const uint4*)(Wrow + kk + e0);
                rb1 = *(const uint4*)(Wrow + kk + e1);
            }
        }
        bf16x8 af[4], bfr[4];
        #pragma unroll
        for (int i = 0; i < 4; ++i)
            af[i] = *(const bf16x8*)&lA[(wm + i * 16 + m16) * 32 + swz];
        #pragma unroll
        for (int j = 0; j < 4; ++j)
            bfr[j] = *(const bf16x8*)&lB[(wn + j * 16 + m16) * 32 + swz];
        #pragma unroll
        for (int i = 0; i < 4; ++i)
            #pragma unroll
            for (int j = 0; j < 4; ++j)
                acc[i][j] = __builtin_amdgcn_mfma_f32_16x16x32_bf16(af[i], bfr[j], acc[i][j], 0, 0, 0);
        __syncthreads();
    }
    // epilogue: D row=(lane>>4)*4+reg, col=lane&15  [verified gfx950 layout]
    const int rowb = (lane >> 4) * 4;
    float* Cf = (float*)C + (size_t)blockIdx.z * czstride;
    unsigned short* Ch = (unsigned short*)C;
    #pragma unroll
    for (int j = 0; j < 4; ++j) {
        const int col = n0 + wn + j * 16 + m16;
        if (col < N) {
            float bv = 0.f;
            if (mode == 1) bv = ldin(bias, boff + col, bf);
            #pragma unroll
            for (int i = 0; i < 4; ++i) {
                #pragma unroll
                for (int r = 0; r < 4; ++r) {
                    const int row = m0 + wm + i * 16 + rowb + r;
                    float v = acc[i][j][r];
                    if (mode == 1) { v += bv; v = (v > 20.f) ? v : log1pf(__expf(v)); }
                    if (mode == 2) Ch[(size_t)row * ldc + col] = f2bf(v);
                    else           Cf[(size_t)row * ldc + col] = v;
                }
            }
        }
    }
}

// ---------------------------------------------------------------------------
// Causal depthwise conv (k=4) + bias + SiLU.  xz is bf16; writes uc bf16.
// ---------------------------------------------------------------------------
__global__ __launch_bounds__(256) void k_conv(
    const unsigned short* __restrict__ xz, const void* __restrict__ cw, size_t cwoff,
    const void* __restrict__ cb, size_t cboff,
    unsigned short* __restrict__ uc,
    const int* __restrict__ flagp)
{
    const bool bf = (*flagp != 0);
    const int idx = blockIdx.x * 256 + threadIdx.x;
    const int d = idx & (DINNER - 1);
    const int l = idx >> 11;
    const float w0 = ldin(cw, cwoff + d * 4 + 0, bf), w1 = ldin(cw, cwoff + d * 4 + 1, bf);
    const float w2 = ldin(cw, cwoff + d * 4 + 2, bf), w3 = ldin(cw, cwoff + d * 4 + 3, bf);
    float acc = ldin(cb, cboff + d, bf);
    if (l >= 3) acc = fmaf(bf2f(xz[(size_t)(l - 3) * (2 * DINNER) + d]), w0, acc);
    if (l >= 2) acc = fmaf(bf2f(xz[(size_t)(l - 2) * (2 * DINNER) + d]), w1, acc);
    if (l >= 1) acc = fmaf(bf2f(xz[(size_t)(l - 1) * (2 * DINNER) + d]), w2, acc);
    acc = fmaf(bf2f(xz[(size_t)l * (2 * DINNER) + d]), w3, acc);
    const float sig = 1.f / (1.f + __expf(-acc));
    uc[(size_t)l * DINNER + d] = f2bf(acc * sig);
}

// ---------------------------------------------------------------------------
// x_proj split-K reduce: xdbl = sum of KSPLIT partials; dual write fp32+bf16.
// ---------------------------------------------------------------------------
__global__ __launch_bounds__(256) void k_reduce(
    const float* __restrict__ parts, float* __restrict__ xdbl,
    unsigned short* __restrict__ xdbl_bf)
{
    const int idx = blockIdx.x * 256 + threadIdx.x;   // 0 .. L*XDIM-1
    float s = 0.f;
    #pragma unroll
    for (int z = 0; z < KSPLIT; ++z)
        s += parts[(size_t)z * L_SEQ * XDIM + idx];
    xdbl[idx] = s;
    xdbl_bf[idx] = f2bf(s);
}

// ---------------------------------------------------------------------------
// out_proj split-K=2 partial add -> hh fp32.
// ---------------------------------------------------------------------------
__global__ __launch_bounds__(256) void k_addparts(
    const float* __restrict__ parts, float* __restrict__ o)
{
    const int i = (blockIdx.x * 256 + threadIdx.x) * 4;
    const float4 a = *(const float4*)(parts + i);
    const float4 b = *(const float4*)(parts + (size_t)L_SEQ * DMODEL + i);
    *(float4*)(o + i) = make_float4(a.x + b.x, a.y + b.y, a.z + b.z, a.w + b.w);
}

// ---------------------------------------------------------------------------
// Chunked selective scan, pass 1: local scan from h=0 per (channels, chunk).
// ---------------------------------------------------------------------------
__global__ __launch_bounds__(128) void k_scan1(
    const float* __restrict__ delta, const unsigned short* __restrict__ uc,
    const float* __restrict__ xdbl,
    const void* __restrict__ Alog, size_t aoff,
    float* __restrict__ hloc, float* __restrict__ sdelta,
    const int* __restrict__ flagp)
{
    const bool bf = (*flagp != 0);
    __shared__ float sB[CHUNK][DSTATE];
    const int d = blockIdx.x * 128 + threadIdx.x;
    const int c = blockIdx.y;
    const int t0 = c * CHUNK;
    float Arow[DSTATE];
    #pragma unroll
    for (int n = 0; n < DSTATE; ++n)
        Arow[n] = -__expf(ldin(Alog, aoff + (size_t)d * DSTATE + n, bf));
    #pragma unroll
    for (int r = 0; r < 8; ++r) {
        const int idx = r * 128 + threadIdx.x;
        const int tt = idx >> 4, n = idx & 15;
        sB[tt][n] = xdbl[(size_t)(t0 + tt) * XDIM + DTRANK + n];
    }
    __syncthreads();
    float h[DSTATE];
    #pragma unroll
    for (int n = 0; n < DSTATE; ++n) h[n] = 0.f;
    float sd = 0.f;
    for (int ti = 0; ti < CHUNK; ++ti) {
        const int t = t0 + ti;
        const float d_t = delta[(size_t)t * DINNER + d];
        const float u_t = bf2f(uc[(size_t)t * DINNER + d]);
        sd += d_t;
        const float du = d_t * u_t;
        #pragma unroll
        for (int n = 0; n < DSTATE; ++n) {
            const float dA = __expf(d_t * Arow[n]);
            h[n] = fmaf(dA, h[n], du * sB[ti][n]);
        }
    }
    float* hp = hloc + ((size_t)c * DINNER + d) * DSTATE;
    #pragma unroll
    for (int n = 0; n < DSTATE; n += 4)
        *(float4*)(hp + n) = make_float4(h[n], h[n + 1], h[n + 2], h[n + 3]);
    sdelta[(size_t)c * DINNER + d] = sd;
}

// ---------------------------------------------------------------------------
// Pass 2: per (d,n) sequential scan over chunk states; in-place -> Hin[c].
// ---------------------------------------------------------------------------
__global__ __launch_bounds__(256) void k_scan2(
    float* __restrict__ hloc, const float* __restrict__ sdelta,
    const void* __restrict__ Alog, size_t aoff,
    const int* __restrict__ flagp)
{
    const bool bf = (*flagp != 0);
    const int gid = blockIdx.x * 256 + threadIdx.x;
    const int d = gid >> 4, n = gid & 15;
    const float A = -__expf(ldin(Alog, aoff + (size_t)d * DSTATE + n, bf));
    float carry = 0.f;
    for (int c = 0; c < NCHUNK; ++c) {
        const size_t idx = ((size_t)c * DINNER + d) * DSTATE + n;
        const float tmp = hloc[idx];
        hloc[idx] = carry;
        const float P = __expf(A * sdelta[(size_t)c * DINNER + d]);
        carry = fmaf(P, carry, tmp);
    }
}

// ---------------------------------------------------------------------------
// Pass 3: local scan seeded with Hin[c]; y=(C.h+uc*D)*silu(z) as bf16.
// z comes from bf16 xz (cols DINNER..2*DINNER).
// ---------------------------------------------------------------------------
__global__ __launch_bounds__(128) void k_scan3(
    const float* __restrict__ delta, const unsigned short* __restrict__ uc,
    const unsigned short* __restrict__ xz, const float* __restrict__ xdbl,
    const void* __restrict__ Alog, size_t aoff,
    const void* __restrict__ Dp, size_t doff,
    const float* __restrict__ hin, unsigned short* __restrict__ y,
    const int* __restrict__ flagp)
{
    const bool bf = (*flagp != 0);
    __shared__ float sBC[CHUNK][2 * DSTATE];
    const int d = blockIdx.x * 128 + threadIdx.x;
    const int c = blockIdx.y;
    const int t0 = c * CHUNK;
    float Arow[DSTATE];
    #pragma unroll
    for (int n = 0; n < DSTATE; ++n)
        Arow[n] = -__expf(ldin(Alog, aoff + (size_t)d * DSTATE + n, bf));
    const float Dv = ldin(Dp, doff + d, bf);
    #pragma unroll
    for (int r = 0; r < 16; ++r) {
        const int idx = r * 128 + threadIdx.x;
        const int tt = idx >> 5, n = idx & 31;
        sBC[tt][n] = xdbl[(size_t)(t0 + tt) * XDIM + DTRANK + n];
    }
    __syncthreads();
    float h[DSTATE];
    const float* hp = hin + ((size_t)c * DINNER + d) * DSTATE;
    #pragma unroll
    for (int n = 0; n < DSTATE; n += 4) {
        const float4 v = *(const float4*)(hp + n);
        h[n] = v.x; h[n + 1] = v.y; h[n + 2] = v.z; h[n + 3] = v.w;
    }
    for (int ti = 0; ti < CHUNK; ++ti) {
        const int t = t0 + ti;
        const float d_t = delta[(size_t)t * DINNER + d];
        const float u_t = bf2f(uc[(size_t)t * DINNER + d]);
        const float z_t = bf2f(xz[(size_t)t * (2 * DINNER) + DINNER + d]);
        const float du = d_t * u_t;
        float dot = 0.f;
        #pragma unroll
        for (int n = 0; n < DSTATE; ++n) {
            const float dA = __expf(d_t * Arow[n]);
            h[n] = fmaf(dA, h[n], du * sBC[ti][n]);
            dot = fmaf(h[n], sBC[ti][DSTATE + n], dot);
        }
        const float sig = 1.f / (1.f + __expf(-z_t));
        y[(size_t)t * DINNER + d] = f2bf((dot + u_t * Dv) * (z_t * sig));
    }
}

// ---------------------------------------------------------------------------
// Final: out = (hidden + residual), dtype per flag
// ---------------------------------------------------------------------------
__global__ __launch_bounds__(256) void k_final(
    const float* __restrict__ hh, const float* __restrict__ resid,
    void* __restrict__ out, const int* __restrict__ flagp)
{
    const bool bf = (*flagp != 0);
    const int i = (blockIdx.x * 256 + threadIdx.x) * 4;
    const float4 a = *(const float4*)(hh + i);
    const float4 b = *(const float4*)(resid + i);
    const float o0 = a.x + b.x, o1 = a.y + b.y, o2 = a.z + b.z, o3 = a.w + b.w;
    if (bf) {
        ushort4 o;
        o.x = f2bf(o0); o.y = f2bf(o1); o.z = f2bf(o2); o.w = f2bf(o3);
        *(ushort4*)((unsigned short*)out + i) = o;
    } else {
        *(float4*)((float*)out + i) = make_float4(o0, o1, o2, o3);
    }
}

extern "C" void kernel_launch(void* const* d_in, const int* in_sizes, int n_in,
                              void* d_out, int out_size, void* d_ws, size_t ws_size,
                              hipStream_t stream)
{
    const void* hs    = d_in[0];
    const void* normw = d_in[1];
    const void* ipw   = d_in[2];
    const void* cw    = d_in[3];
    const void* cb    = d_in[4];
    const void* xpw   = d_in[5];
    const void* dtw   = d_in[6];
    const void* dtb   = d_in[7];
    const void* Alog  = d_in[8];
    const void* Dp    = d_in[9];
    const void* opw   = d_in[10];

    // fp32 region (~34 MB)
    float* ws    = (float*)d_ws;
    float* resid = ws;                                       // 2M floats
    float* hh    = resid  + (size_t)L_SEQ * DMODEL;          // 2M (scan scratch overlay)
    float* xdblb = hh     + (size_t)L_SEQ * DMODEL;          // 196608
    float* deltab= xdblb  + (size_t)L_SEQ * XDIM;            // 4.19M (parts overlays)
    // bf16 region (~51 MB)
    unsigned short* hn_bf   = (unsigned short*)(deltab + (size_t)L_SEQ * DINNER);
    unsigned short* xz_bf   = hn_bf   + (size_t)L_SEQ * DMODEL;      // L*4096
    unsigned short* uc_bf   = xz_bf   + (size_t)L_SEQ * 2 * DINNER;  // L*2048
    unsigned short* xdbl_bf = uc_bf   + (size_t)L_SEQ * DINNER;      // L*96
    unsigned short* y_bf    = xdbl_bf + (size_t)L_SEQ * XDIM;        // L*2048
    // per-layer converted weights (bf16): ipw 4.19M, xpw 196K, dtw 131K, opw 2.1M
    unsigned short* w_ip    = y_bf   + (size_t)L_SEQ * DINNER;
    unsigned short* w_xp    = w_ip   + (size_t)2 * DINNER * DMODEL;
    unsigned short* w_dt    = w_xp   + (size_t)XDIM * DINNER;
    unsigned short* w_op    = w_dt   + (size_t)DINNER * DTRANK;
    int*            flagp   = (int*)(w_op + (size_t)DMODEL * DINNER);

    // scan scratch overlays hh (dead between addnorm-read and addparts-write)
    float* hlocb   = hh;                                     // 1,048,576 floats
    float* sdeltab = hh + (size_t)NCHUNK * DINNER * DSTATE;  // 65,536 floats
    // x_proj / out_proj partials overlay deltab
    float* partsX  = deltab;   // KSPLIT*L*XDIM   = 3,145,728 <= 4,194,304
    float* partsO  = deltab;   // 2*L*DMODEL      = 4,194,304 == capacity

    k_detect<<<1, 1, 0, stream>>>((const unsigned int*)Alog, flagp);

    for (int i = 0; i < NLAYER; ++i) {
        const size_t o_ipw = (size_t)i * 2 * DINNER * DMODEL;
        const size_t o_xpw = (size_t)i * XDIM * DINNER;
        const size_t o_dtw = (size_t)i * DINNER * DTRANK;
        const size_t o_opw = (size_t)i * DMODEL * DINNER;
        const size_t o_al  = (size_t)i * DINNER * DSTATE;

        // per-layer weight pre-cast (no-op when inputs are bf16)
        k_castw<<<(2 * DINNER * DMODEL) / 1024, 256, 0, stream>>>(
            ipw, o_ipw, w_ip, 2 * DINNER * DMODEL, flagp);
        k_castw<<<(XDIM * DINNER) / 1024, 256, 0, stream>>>(
            xpw, o_xpw, w_xp, XDIM * DINNER, flagp);
        k_castw<<<(DINNER * DTRANK) / 1024, 256, 0, stream>>>(
            dtw, o_dtw, w_dt, DINNER * DTRANK, flagp);
        k_castw<<<(DMODEL * DINNER) / 1024, 256, 0, stream>>>(
            opw, o_opw, w_op, DMODEL * DINNER, flagp);

        k_addnorm<<<L_SEQ, 256, 0, stream>>>(
            hh, hs, resid, hn_bf, normw, (size_t)i * DMODEL, i == 0 ? 1 : 0, flagp);
        // in_proj: (2048 x 1024) @ (4096 x 1024)^T -> xz bf16  [grid: n-major]
        k_gemm_mfma<<<dim3(32, 16, 1), 256, 0, stream>>>(
            hn_bf, DMODEL, ipw, o_ipw, w_ip, DMODEL,
            xz_bf, 2 * DINNER, 0, 2 * DINNER, DMODEL, nullptr, 0, 2, flagp);
        k_conv<<<(L_SEQ * DINNER) / 256, 256, 0, stream>>>(
            xz_bf, cw, (size_t)i * DINNER * DCONV, cb, (size_t)i * DINNER, uc_bf, flagp);
        // x_proj split-K=16: (2048 x 2048) @ (96 x 2048)^T -> partials fp32
        k_gemm_mfma<<<dim3(1, 16, KSPLIT), 256, 0, stream>>>(
            uc_bf, DINNER, xpw, o_xpw, w_xp, DINNER,
            partsX, XDIM, (size_t)L_SEQ * XDIM, XDIM, DINNER / KSPLIT,
            nullptr, 0, 0, flagp);
        k_reduce<<<(L_SEQ * XDIM) / 256, 256, 0, stream>>>(partsX, xdblb, xdbl_bf);
        // dt_proj + softplus: (2048 x 64) @ (2048 x 64)^T -> delta fp32
        k_gemm_mfma<<<dim3(16, 16, 1), 256, 0, stream>>>(
            xdbl_bf, XDIM, dtw, o_dtw, w_dt, DTRANK,
            deltab, DINNER, 0, DINNER, DTRANK, dtb, (size_t)i * DINNER, 1, flagp);
        // chunk-parallel selective scan
        k_scan1<<<dim3(DINNER / 128, NCHUNK), 128, 0, stream>>>(
            deltab, uc_bf, xdblb, Alog, o_al, hlocb, sdeltab, flagp);
        k_scan2<<<(DINNER * DSTATE) / 256, 256, 0, stream>>>(
            hlocb, sdeltab, Alog, o_al, flagp);
        k_scan3<<<dim3(DINNER / 128, NCHUNK), 128, 0, stream>>>(
            deltab, uc_bf, xz_bf, xdblb, Alog, o_al, Dp, (size_t)i * DINNER,
            hlocb, y_bf, flagp);
        // out_proj split-K=2: (2048 x 2048) @ (1024 x 2048)^T -> partials fp32
        k_gemm_mfma<<<dim3(8, 16, 2), 256, 0, stream>>>(
            y_bf, DINNER, opw, o_opw, w_op, DINNER,
            partsO, DMODEL, (size_t)L_SEQ * DMODEL, DMODEL, DINNER / 2,
            nullptr, 0, 0, flagp);
        k_addparts<<<(L_SEQ * DMODEL) / 1024, 256, 0, stream>>>(partsO, hh);
    }
    k_final<<<(L_SEQ * DMODEL) / 1024, 256, 0, stream>>>(hh, resid, d_out, flagp);
}

// Round 7
// 1020.674 us; speedup vs baseline: 7.4316x; 1.0995x over previous
//
#include <hip/hip_runtime.h>
#include <hip/hip_bf16.h>

// Problem constants (from reference)
#define L_SEQ   2048
#define DMODEL  1024
#define DINNER  2048
#define DSTATE  16
#define DTRANK  64
#define DCONV   4
#define NLAYER  4
#define XDIM    96   // DTRANK + 2*DSTATE
#define CHUNK   32
#define NCHUNK  (L_SEQ / CHUNK)   // 64
#define KSPLIT  16                // x_proj split-K factor
#define LOG2E   1.4426950408889634f

typedef __attribute__((ext_vector_type(8))) short bf16x8;
typedef __attribute__((ext_vector_type(4))) float f32x4;

__device__ __forceinline__ float bf2f(unsigned short u) {
    union { unsigned int i; float f; } v; v.i = ((unsigned int)u) << 16; return v.f;
}
__device__ __forceinline__ unsigned short f2bf(float f) {
    union { float f; unsigned int i; } v; v.f = f;
    unsigned int x = v.i;
    unsigned int r = (x + 0x7fffu + ((x >> 16) & 1u)) >> 16;  // RTNE
    return (unsigned short)r;
}
__device__ __forceinline__ float ldin(const void* p, size_t idx, bool bf) {
    return bf ? bf2f(((const unsigned short*)p)[idx]) : ((const float*)p)[idx];
}

// ---------------------------------------------------------------------------
// Dtype detector: A_log[0] = log(1) = 0.  fp32 -> first u32 == 0x00000000.
// ---------------------------------------------------------------------------
__global__ void k_detect(const unsigned int* __restrict__ Alog_u32, int* __restrict__ flag) {
    *flag = (Alog_u32[0] != 0u) ? 1 : 0;
}

// ---------------------------------------------------------------------------
// Combined per-layer weight cast fp32 -> bf16 (one launch for all 4 weights;
// no-op when inputs already bf16 — GEMMs then read the original pointers).
// ---------------------------------------------------------------------------
#define N_IP (2 * DINNER * DMODEL)   // 4,194,304
#define N_XP (XDIM * DINNER)         //   196,608
#define N_DT (DINNER * DTRANK)       //   131,072
#define N_OP (DMODEL * DINNER)       // 2,097,152
#define N_CAST_TOT (N_IP + N_XP + N_DT + N_OP)

__global__ __launch_bounds__(256) void k_castall(
    const void* __restrict__ ipw, const void* __restrict__ xpw,
    const void* __restrict__ dtw, const void* __restrict__ opw,
    size_t o_ip, size_t o_xp, size_t o_dt, size_t o_op,
    unsigned short* __restrict__ w_ip, unsigned short* __restrict__ w_xp,
    unsigned short* __restrict__ w_dt, unsigned short* __restrict__ w_op,
    const int* __restrict__ flagp)
{
    if (*flagp) return;
    int i = (blockIdx.x * 256 + threadIdx.x) * 4;
    const float* src; unsigned short* dst;
    if (i < N_IP)                       { src = (const float*)ipw + o_ip + i; dst = w_ip + i; }
    else if ((i -= N_IP) < N_XP)        { src = (const float*)xpw + o_xp + i; dst = w_xp + i; }
    else if ((i -= N_XP) < N_DT)        { src = (const float*)dtw + o_dt + i; dst = w_dt + i; }
    else if ((i -= N_DT) < N_OP)        { src = (const float*)opw + o_op + i; dst = w_op + i; }
    else return;
    const float4 v = *(const float4*)src;
    ushort4 o;
    o.x = f2bf(v.x); o.y = f2bf(v.y); o.z = f2bf(v.z); o.w = f2bf(v.w);
    *(ushort4*)dst = o;
}

// ---------------------------------------------------------------------------
// Fused residual add + RMSNorm -> bf16 normed output.
// ---------------------------------------------------------------------------
__global__ __launch_bounds__(256) void k_addnorm(
    const float* __restrict__ hid, const void* __restrict__ hs,
    float* __restrict__ resid, unsigned short* __restrict__ hnorm,
    const void* __restrict__ w, size_t woff, int first,
    const int* __restrict__ flagp)
{
    const bool bf = (*flagp != 0);
    const int row = blockIdx.x;
    const int col = threadIdx.x * 4;
    const size_t base = (size_t)row * DMODEL + col;
    float r[4];
    if (first) {
        if (bf) {
            const ushort4 v = *(const ushort4*)((const unsigned short*)hs + base);
            r[0] = bf2f(v.x); r[1] = bf2f(v.y); r[2] = bf2f(v.z); r[3] = bf2f(v.w);
        } else {
            const float4 v = *(const float4*)((const float*)hs + base);
            r[0] = v.x; r[1] = v.y; r[2] = v.z; r[3] = v.w;
        }
    } else {
        const float4 hv = *(const float4*)(hid + base);
        const float4 rv = *(const float4*)(resid + base);
        r[0] = hv.x + rv.x; r[1] = hv.y + rv.y; r[2] = hv.z + rv.z; r[3] = hv.w + rv.w;
    }
    *(float4*)(resid + base) = make_float4(r[0], r[1], r[2], r[3]);
    float ss = r[0]*r[0] + r[1]*r[1] + r[2]*r[2] + r[3]*r[3];
    #pragma unroll
    for (int o = 32; o > 0; o >>= 1) ss += __shfl_down(ss, o);
    __shared__ float red[4];
    const int lane = threadIdx.x & 63, wv = threadIdx.x >> 6;
    if (lane == 0) red[wv] = ss;
    __syncthreads();
    const float total = red[0] + red[1] + red[2] + red[3];
    const float scale = rsqrtf(total * (1.0f / DMODEL) + 1e-5f);
    const float w0 = ldin(w, woff + col + 0, bf), w1 = ldin(w, woff + col + 1, bf);
    const float w2 = ldin(w, woff + col + 2, bf), w3 = ldin(w, woff + col + 3, bf);
    ushort4 o;
    o.x = f2bf(r[0] * scale * w0); o.y = f2bf(r[1] * scale * w1);
    o.z = f2bf(r[2] * scale * w2); o.w = f2bf(r[3] * scale * w3);
    *(ushort4*)(hnorm + base) = o;
}

// ---------------------------------------------------------------------------
// MFMA NT GEMM: C[M,N] = A[M,K]_bf16 * W[N,K]^T_bf16.
// Grid: blockIdx.x = n-tile (L2/XCD locality), blockIdx.y = m-tile.
// 128x128 tile, 256 thr, BK=32, swizzled LDS, register prefetch.
// blockIdx.z = split-K slice.  mode: 0 fp32 C, 1 softplus+bias fp32, 2 bf16 C.
// ---------------------------------------------------------------------------
__global__ __launch_bounds__(256) void k_gemm_mfma(
    const unsigned short* __restrict__ A, int lda,
    const void* __restrict__ Worig, size_t woff,
    const unsigned short* __restrict__ Wconv, int ldw,
    void* __restrict__ C, int ldc, size_t czstride,
    int N, int Kslice,
    const void* __restrict__ bias, size_t boff, int mode,
    const int* __restrict__ flagp)
{
    const bool bf = (*flagp != 0);
    __shared__ unsigned short lA[128 * 32];
    __shared__ unsigned short lB[128 * 32];
    const int tid = threadIdx.x;
    const int n0 = blockIdx.x * 128;
    const int m0 = blockIdx.y * 128;
    const int k0 = blockIdx.z * Kslice;

    const int w    = tid >> 6;
    const int lane = tid & 63;
    const int wm = (w >> 1) * 64, wn = (w & 1) * 64;
    const int m16 = lane & 15, kg = lane >> 4;
    const int swz = (kg ^ (m16 & 3)) * 8;

    const int sr  = tid >> 1;
    const int cb0 = tid & 1;
    const int e0  = cb0 * 8, e1 = e0 + 16;
    const int p0  = (cb0 ^ (sr & 3)) * 8;
    const int p1  = ((cb0 + 2) ^ (sr & 3)) * 8;
    const int sA  = sr * 32;

    const unsigned short* Arow = A + (size_t)(m0 + sr) * lda;
    const int nrow = n0 + sr;
    const bool nok = (nrow < N);
    const unsigned short* Wbase = bf ? ((const unsigned short*)Worig + woff) : Wconv;
    const unsigned short* Wrow  = Wbase + (size_t)nrow * ldw;

    f32x4 acc[4][4];
    #pragma unroll
    for (int i = 0; i < 4; ++i)
        #pragma unroll
        for (int j = 0; j < 4; ++j)
            acc[i][j] = (f32x4){0.f, 0.f, 0.f, 0.f};

    uint4 ra0, ra1, rb0, rb1;
    ra0 = *(const uint4*)(Arow + k0 + e0);
    ra1 = *(const uint4*)(Arow + k0 + e1);
    rb0 = (uint4){0u,0u,0u,0u}; rb1 = rb0;
    if (nok) {
        rb0 = *(const uint4*)(Wrow + k0 + e0);
        rb1 = *(const uint4*)(Wrow + k0 + e1);
    }

    for (int kb = 0; kb < Kslice; kb += 32) {
        *(uint4*)&lA[sA + p0] = ra0;
        *(uint4*)&lA[sA + p1] = ra1;
        *(uint4*)&lB[sA + p0] = rb0;
        *(uint4*)&lB[sA + p1] = rb1;
        __syncthreads();
        if (kb + 32 < Kslice) {
            const int kk = k0 + kb + 32;
            ra0 = *(const uint4*)(Arow + kk + e0);
            ra1 = *(const uint4*)(Arow + kk + e1);
            if (nok) {
                rb0 = *(const uint4*)(Wrow + kk + e0);
                rb1 = *(const uint4*)(Wrow + kk + e1);
            }
        }
        bf16x8 af[4], bfr[4];
        #pragma unroll
        for (int i = 0; i < 4; ++i)
            af[i] = *(const bf16x8*)&lA[(wm + i * 16 + m16) * 32 + swz];
        #pragma unroll
        for (int j = 0; j < 4; ++j)
            bfr[j] = *(const bf16x8*)&lB[(wn + j * 16 + m16) * 32 + swz];
        #pragma unroll
        for (int i = 0; i < 4; ++i)
            #pragma unroll
            for (int j = 0; j < 4; ++j)
                acc[i][j] = __builtin_amdgcn_mfma_f32_16x16x32_bf16(af[i], bfr[j], acc[i][j], 0, 0, 0);
        __syncthreads();
    }
    const int rowb = (lane >> 4) * 4;
    float* Cf = (float*)C + (size_t)blockIdx.z * czstride;
    unsigned short* Ch = (unsigned short*)C;
    #pragma unroll
    for (int j = 0; j < 4; ++j) {
        const int col = n0 + wn + j * 16 + m16;
        if (col < N) {
            float bv = 0.f;
            if (mode == 1) bv = ldin(bias, boff + col, bf);
            #pragma unroll
            for (int i = 0; i < 4; ++i) {
                #pragma unroll
                for (int r = 0; r < 4; ++r) {
                    const int row = m0 + wm + i * 16 + rowb + r;
                    float v = acc[i][j][r];
                    if (mode == 1) { v += bv; v = (v > 20.f) ? v : log1pf(__expf(v)); }
                    if (mode == 2) Ch[(size_t)row * ldc + col] = f2bf(v);
                    else           Cf[(size_t)row * ldc + col] = v;
                }
            }
        }
    }
}

// ---------------------------------------------------------------------------
// Causal depthwise conv (k=4) + bias + SiLU.  xz bf16 -> uc bf16.
// ---------------------------------------------------------------------------
__global__ __launch_bounds__(256) void k_conv(
    const unsigned short* __restrict__ xz, const void* __restrict__ cw, size_t cwoff,
    const void* __restrict__ cb, size_t cboff,
    unsigned short* __restrict__ uc,
    const int* __restrict__ flagp)
{
    const bool bf = (*flagp != 0);
    const int idx = blockIdx.x * 256 + threadIdx.x;
    const int d = idx & (DINNER - 1);
    const int l = idx >> 11;
    const float w0 = ldin(cw, cwoff + d * 4 + 0, bf), w1 = ldin(cw, cwoff + d * 4 + 1, bf);
    const float w2 = ldin(cw, cwoff + d * 4 + 2, bf), w3 = ldin(cw, cwoff + d * 4 + 3, bf);
    float acc = ldin(cb, cboff + d, bf);
    if (l >= 3) acc = fmaf(bf2f(xz[(size_t)(l - 3) * (2 * DINNER) + d]), w0, acc);
    if (l >= 2) acc = fmaf(bf2f(xz[(size_t)(l - 2) * (2 * DINNER) + d]), w1, acc);
    if (l >= 1) acc = fmaf(bf2f(xz[(size_t)(l - 1) * (2 * DINNER) + d]), w2, acc);
    acc = fmaf(bf2f(xz[(size_t)l * (2 * DINNER) + d]), w3, acc);
    const float sig = 1.f / (1.f + __expf(-acc));
    uc[(size_t)l * DINNER + d] = f2bf(acc * sig);
}

// ---------------------------------------------------------------------------
// x_proj split-K reduce: xdbl = sum of KSPLIT partials; dual write fp32+bf16.
// ---------------------------------------------------------------------------
__global__ __launch_bounds__(256) void k_reduce(
    const float* __restrict__ parts, float* __restrict__ xdbl,
    unsigned short* __restrict__ xdbl_bf)
{
    const int idx = blockIdx.x * 256 + threadIdx.x;
    float s = 0.f;
    #pragma unroll
    for (int z = 0; z < KSPLIT; ++z)
        s += parts[(size_t)z * L_SEQ * XDIM + idx];
    xdbl[idx] = s;
    xdbl_bf[idx] = f2bf(s);
}

// ---------------------------------------------------------------------------
// out_proj split-K=2 partial add -> hh fp32.
// ---------------------------------------------------------------------------
__global__ __launch_bounds__(256) void k_addparts(
    const float* __restrict__ parts, float* __restrict__ o)
{
    const int i = (blockIdx.x * 256 + threadIdx.x) * 4;
    const float4 a = *(const float4*)(parts + i);
    const float4 b = *(const float4*)(parts + (size_t)L_SEQ * DMODEL + i);
    *(float4*)(o + i) = make_float4(a.x + b.x, a.y + b.y, a.z + b.z, a.w + b.w);
}

// ---------------------------------------------------------------------------
// Chunked selective scan, pass 1: local scan from h=0 per (channels, chunk).
// A pre-scaled by log2e -> exp2f (bare v_exp_f32). Next-step prefetch.
// ---------------------------------------------------------------------------
__global__ __launch_bounds__(128) void k_scan1(
    const float* __restrict__ delta, const unsigned short* __restrict__ uc,
    const float* __restrict__ xdbl,
    const void* __restrict__ Alog, size_t aoff,
    float* __restrict__ hloc, float* __restrict__ sdelta,
    const int* __restrict__ flagp)
{
    const bool bf = (*flagp != 0);
    __shared__ float sB[CHUNK][DSTATE];
    const int d = blockIdx.x * 128 + threadIdx.x;
    const int c = blockIdx.y;
    const int t0 = c * CHUNK;
    float A2[DSTATE];
    #pragma unroll
    for (int n = 0; n < DSTATE; ++n)
        A2[n] = -__expf(ldin(Alog, aoff + (size_t)d * DSTATE + n, bf)) * LOG2E;
    #pragma unroll
    for (int r = 0; r < 4; ++r) {
        const int idx = r * 128 + threadIdx.x;   // 0..511
        const int tt = idx >> 4, n = idx & 15;
        sB[tt][n] = xdbl[(size_t)(t0 + tt) * XDIM + DTRANK + n];
    }
    __syncthreads();
    float h[DSTATE];
    #pragma unroll
    for (int n = 0; n < DSTATE; ++n) h[n] = 0.f;
    float sd = 0.f;
    float dcur = delta[(size_t)t0 * DINNER + d];
    float ucur = bf2f(uc[(size_t)t0 * DINNER + d]);
    for (int ti = 0; ti < CHUNK; ++ti) {
        float dnx = 0.f, unx = 0.f;
        if (ti < CHUNK - 1) {
            const size_t nxt = (size_t)(t0 + ti + 1) * DINNER + d;
            dnx = delta[nxt];
            unx = bf2f(uc[nxt]);
        }
        sd += dcur;
        const float du = dcur * ucur;
        #pragma unroll
        for (int n = 0; n < DSTATE; ++n) {
            const float dA = exp2f(dcur * A2[n]);
            h[n] = fmaf(dA, h[n], du * sB[ti][n]);
        }
        dcur = dnx; ucur = unx;
    }
    float* hp = hloc + ((size_t)c * DINNER + d) * DSTATE;
    #pragma unroll
    for (int n = 0; n < DSTATE; n += 4)
        *(float4*)(hp + n) = make_float4(h[n], h[n + 1], h[n + 2], h[n + 3]);
    sdelta[(size_t)c * DINNER + d] = sd;
}

// ---------------------------------------------------------------------------
// Pass 2: per (d,n) sequential scan over chunk states; in-place -> Hin[c].
// ---------------------------------------------------------------------------
__global__ __launch_bounds__(256) void k_scan2(
    float* __restrict__ hloc, const float* __restrict__ sdelta,
    const void* __restrict__ Alog, size_t aoff,
    const int* __restrict__ flagp)
{
    const bool bf = (*flagp != 0);
    const int gid = blockIdx.x * 256 + threadIdx.x;
    const int d = gid >> 4, n = gid & 15;
    const float A2 = -__expf(ldin(Alog, aoff + (size_t)d * DSTATE + n, bf)) * LOG2E;
    float carry = 0.f;
    for (int c = 0; c < NCHUNK; ++c) {
        const size_t idx = ((size_t)c * DINNER + d) * DSTATE + n;
        const float tmp = hloc[idx];
        hloc[idx] = carry;
        const float P = exp2f(A2 * sdelta[(size_t)c * DINNER + d]);
        carry = fmaf(P, carry, tmp);
    }
}

// ---------------------------------------------------------------------------
// Pass 3: local scan seeded with Hin[c]; y=(C.h+uc*D)*silu(z) as bf16.
// exp2-folded A, next-step prefetch of delta/uc/z streams.
// ---------------------------------------------------------------------------
__global__ __launch_bounds__(128) void k_scan3(
    const float* __restrict__ delta, const unsigned short* __restrict__ uc,
    const unsigned short* __restrict__ xz, const float* __restrict__ xdbl,
    const void* __restrict__ Alog, size_t aoff,
    const void* __restrict__ Dp, size_t doff,
    const float* __restrict__ hin, unsigned short* __restrict__ y,
    const int* __restrict__ flagp)
{
    const bool bf = (*flagp != 0);
    __shared__ float sBC[CHUNK][2 * DSTATE];
    const int d = blockIdx.x * 128 + threadIdx.x;
    const int c = blockIdx.y;
    const int t0 = c * CHUNK;
    float A2[DSTATE];
    #pragma unroll
    for (int n = 0; n < DSTATE; ++n)
        A2[n] = -__expf(ldin(Alog, aoff + (size_t)d * DSTATE + n, bf)) * LOG2E;
    const float Dv = ldin(Dp, doff + d, bf);
    #pragma unroll
    for (int r = 0; r < 8; ++r) {
        const int idx = r * 128 + threadIdx.x;   // 0..1023
        const int tt = idx >> 5, n = idx & 31;
        sBC[tt][n] = xdbl[(size_t)(t0 + tt) * XDIM + DTRANK + n];
    }
    __syncthreads();
    float h[DSTATE];
    const float* hp = hin + ((size_t)c * DINNER + d) * DSTATE;
    #pragma unroll
    for (int n = 0; n < DSTATE; n += 4) {
        const float4 v = *(const float4*)(hp + n);
        h[n] = v.x; h[n + 1] = v.y; h[n + 2] = v.z; h[n + 3] = v.w;
    }
    float dcur = delta[(size_t)t0 * DINNER + d];
    float ucur = bf2f(uc[(size_t)t0 * DINNER + d]);
    float zcur = bf2f(xz[(size_t)t0 * (2 * DINNER) + DINNER + d]);
    for (int ti = 0; ti < CHUNK; ++ti) {
        float dnx = 0.f, unx = 0.f, znx = 0.f;
        if (ti < CHUNK - 1) {
            const size_t nxt = (size_t)(t0 + ti + 1) * DINNER + d;
            dnx = delta[nxt];
            unx = bf2f(uc[nxt]);
            znx = bf2f(xz[(size_t)(t0 + ti + 1) * (2 * DINNER) + DINNER + d]);
        }
        const float du = dcur * ucur;
        float dot = 0.f;
        #pragma unroll
        for (int n = 0; n < DSTATE; ++n) {
            const float dA = exp2f(dcur * A2[n]);
            h[n] = fmaf(dA, h[n], du * sBC[ti][n]);
            dot = fmaf(h[n], sBC[ti][DSTATE + n], dot);
        }
        const float sig = 1.f / (1.f + __expf(-zcur));
        y[(size_t)(t0 + ti) * DINNER + d] = f2bf((dot + ucur * Dv) * (zcur * sig));
        dcur = dnx; ucur = unx; zcur = znx;
    }
}

// ---------------------------------------------------------------------------
// Final: out = (hidden + residual), dtype per flag
// ---------------------------------------------------------------------------
__global__ __launch_bounds__(256) void k_final(
    const float* __restrict__ hh, const float* __restrict__ resid,
    void* __restrict__ out, const int* __restrict__ flagp)
{
    const bool bf = (*flagp != 0);
    const int i = (blockIdx.x * 256 + threadIdx.x) * 4;
    const float4 a = *(const float4*)(hh + i);
    const float4 b = *(const float4*)(resid + i);
    const float o0 = a.x + b.x, o1 = a.y + b.y, o2 = a.z + b.z, o3 = a.w + b.w;
    if (bf) {
        ushort4 o;
        o.x = f2bf(o0); o.y = f2bf(o1); o.z = f2bf(o2); o.w = f2bf(o3);
        *(ushort4*)((unsigned short*)out + i) = o;
    } else {
        *(float4*)((float*)out + i) = make_float4(o0, o1, o2, o3);
    }
}

extern "C" void kernel_launch(void* const* d_in, const int* in_sizes, int n_in,
                              void* d_out, int out_size, void* d_ws, size_t ws_size,
                              hipStream_t stream)
{
    const void* hs    = d_in[0];
    const void* normw = d_in[1];
    const void* ipw   = d_in[2];
    const void* cw    = d_in[3];
    const void* cb    = d_in[4];
    const void* xpw   = d_in[5];
    const void* dtw   = d_in[6];
    const void* dtb   = d_in[7];
    const void* Alog  = d_in[8];
    const void* Dp    = d_in[9];
    const void* opw   = d_in[10];

    // fp32 region (~43 MB)
    float* ws     = (float*)d_ws;
    float* resid  = ws;                                        // 2,097,152
    float* hh     = resid  + (size_t)L_SEQ * DMODEL;           // 2,097,152
    float* xdblb  = hh     + (size_t)L_SEQ * DMODEL;           //   196,608
    float* deltab = xdblb  + (size_t)L_SEQ * XDIM;             // 4,194,304 (parts overlays)
    float* hlocb  = deltab + (size_t)L_SEQ * DINNER;           // 2,097,152 (NCHUNK*DINNER*DSTATE)
    float* sdeltab= hlocb  + (size_t)NCHUNK * DINNER * DSTATE; //   131,072
    // bf16 region (~51 MB)
    unsigned short* hn_bf   = (unsigned short*)(sdeltab + (size_t)NCHUNK * DINNER);
    unsigned short* xz_bf   = hn_bf   + (size_t)L_SEQ * DMODEL;
    unsigned short* uc_bf   = xz_bf   + (size_t)L_SEQ * 2 * DINNER;
    unsigned short* xdbl_bf = uc_bf   + (size_t)L_SEQ * DINNER;
    unsigned short* y_bf    = xdbl_bf + (size_t)L_SEQ * XDIM;
    unsigned short* w_ip    = y_bf   + (size_t)L_SEQ * DINNER;
    unsigned short* w_xp    = w_ip   + (size_t)2 * DINNER * DMODEL;
    unsigned short* w_dt    = w_xp   + (size_t)XDIM * DINNER;
    unsigned short* w_op    = w_dt   + (size_t)DINNER * DTRANK;
    int*            flagp   = (int*)(w_op + (size_t)DMODEL * DINNER);

    // x_proj / out_proj partials overlay deltab (in-order stream makes it safe)
    float* partsX  = deltab;   // KSPLIT*L*XDIM = 3,145,728 <= 4,194,304
    float* partsO  = deltab;   // 2*L*DMODEL    = 4,194,304 == capacity

    k_detect<<<1, 1, 0, stream>>>((const unsigned int*)Alog, flagp);

    for (int i = 0; i < NLAYER; ++i) {
        const size_t o_ipw = (size_t)i * 2 * DINNER * DMODEL;
        const size_t o_xpw = (size_t)i * XDIM * DINNER;
        const size_t o_dtw = (size_t)i * DINNER * DTRANK;
        const size_t o_opw = (size_t)i * DMODEL * DINNER;
        const size_t o_al  = (size_t)i * DINNER * DSTATE;

        // combined per-layer weight cast (no-op when inputs are bf16)
        k_castall<<<(N_CAST_TOT / 4 + 255) / 256, 256, 0, stream>>>(
            ipw, xpw, dtw, opw, o_ipw, o_xpw, o_dtw, o_opw,
            w_ip, w_xp, w_dt, w_op, flagp);

        k_addnorm<<<L_SEQ, 256, 0, stream>>>(
            hh, hs, resid, hn_bf, normw, (size_t)i * DMODEL, i == 0 ? 1 : 0, flagp);
        // in_proj: (2048 x 1024) @ (4096 x 1024)^T -> xz bf16  [grid n-major]
        k_gemm_mfma<<<dim3(32, 16, 1), 256, 0, stream>>>(
            hn_bf, DMODEL, ipw, o_ipw, w_ip, DMODEL,
            xz_bf, 2 * DINNER, 0, 2 * DINNER, DMODEL, nullptr, 0, 2, flagp);
        k_conv<<<(L_SEQ * DINNER) / 256, 256, 0, stream>>>(
            xz_bf, cw, (size_t)i * DINNER * DCONV, cb, (size_t)i * DINNER, uc_bf, flagp);
        // x_proj split-K=16: (2048 x 2048) @ (96 x 2048)^T -> partials fp32
        k_gemm_mfma<<<dim3(1, 16, KSPLIT), 256, 0, stream>>>(
            uc_bf, DINNER, xpw, o_xpw, w_xp, DINNER,
            partsX, XDIM, (size_t)L_SEQ * XDIM, XDIM, DINNER / KSPLIT,
            nullptr, 0, 0, flagp);
        k_reduce<<<(L_SEQ * XDIM) / 256, 256, 0, stream>>>(partsX, xdblb, xdbl_bf);
        // dt_proj + softplus: (2048 x 64) @ (2048 x 64)^T -> delta fp32
        k_gemm_mfma<<<dim3(16, 16, 1), 256, 0, stream>>>(
            xdbl_bf, XDIM, dtw, o_dtw, w_dt, DTRANK,
            deltab, DINNER, 0, DINNER, DTRANK, dtb, (size_t)i * DINNER, 1, flagp);
        // chunk-parallel selective scan (CHUNK=32 -> 1024 blocks/pass)
        k_scan1<<<dim3(DINNER / 128, NCHUNK), 128, 0, stream>>>(
            deltab, uc_bf, xdblb, Alog, o_al, hlocb, sdeltab, flagp);
        k_scan2<<<(DINNER * DSTATE) / 256, 256, 0, stream>>>(
            hlocb, sdeltab, Alog, o_al, flagp);
        k_scan3<<<dim3(DINNER / 128, NCHUNK), 128, 0, stream>>>(
            deltab, uc_bf, xz_bf, xdblb, Alog, o_al, Dp, (size_t)i * DINNER,
            hlocb, y_bf, flagp);
        // out_proj split-K=2: (2048 x 2048) @ (1024 x 2048)^T -> partials fp32
        k_gemm_mfma<<<dim3(8, 16, 2), 256, 0, stream>>>(
            y_bf, DINNER, opw, o_opw, w_op, DINNER,
            partsO, DMODEL, (size_t)L_SEQ * DMODEL, DMODEL, DINNER / 2,
            nullptr, 0, 0, flagp);
        k_addparts<<<(L_SEQ * DMODEL) / 1024, 256, 0, stream>>>(partsO, hh);
    }
    k_final<<<(L_SEQ * DMODEL) / 1024, 256, 0, stream>>>(hh, resid, d_out, flagp);
}